// Round 9
// baseline (1536.080 us; speedup 1.0000x reference)
//
#include <hip/hip_runtime.h>
#include <hip/hip_cooperative_groups.h>
#include <cstdint>
#include <cstddef>

typedef __attribute__((ext_vector_type(8))) short short8;   // 8 bf16 (4 VGPRs) MFMA frag
typedef __attribute__((ext_vector_type(4))) float floatx4;  // MFMA accumulator

#define T_STEPS 128
#define BATCH   256
#define IDIM    512
#define HDIM    512
#define KHIST   32
#define RDEPTH  16

// LDS layout (recurrent2)
#define WA_STRIDE 520      // 512 + 8 pad
#define WB_STRIDE 1032     // 1024 + 8 pad
#define LDS_BYTES 148480   // B: WB 64*1032*2 + EX 16384; A: 49920 + 65536

// flags: one per 128B LLC line (FSTR ints apart)
#define FSTR 32
#define POLL_SLEEP 8
// pure-handshake probe: 256 steps of the r5 flag protocol, no data/compute.
// Its duration (total - recurrent2 - ~215us overhead) measures the idle
// lockstep handshake cost per step directly.
#define PROBE_STEPS 256

__device__ __forceinline__ unsigned short f2bf(float x) {
  union { float f; unsigned u; } v; v.f = x;
  unsigned r = v.u + 0x7fffu + ((v.u >> 16) & 1u);   // RNE
  return (unsigned short)(r >> 16);
}
__device__ __forceinline__ float bf2f(unsigned short s) {
  union { unsigned u; float f; } v; v.u = ((unsigned)s) << 16; return v.f;
}
__device__ __forceinline__ float sigm(float x) { return 1.0f / (1.0f + __expf(-x)); }
__device__ __forceinline__ float tanh_f(float x) {
  float ax = fabsf(x);
  float e = __expf(-2.0f * ax);
  float t = (1.0f - e) / (1.0f + e);
  return x < 0.0f ? -t : t;
}

// ---- LLC-coherent exchange (r6-proven protocol: sc0 sc1 everywhere) ----
__device__ __forceinline__ void llc_load_1k(const unsigned short* p, short8* r) {
  asm volatile(
    "global_load_dwordx4 %0,  %16, off sc0 sc1\n\t"
    "global_load_dwordx4 %1,  %16, off offset:64 sc0 sc1\n\t"
    "global_load_dwordx4 %2,  %16, off offset:128 sc0 sc1\n\t"
    "global_load_dwordx4 %3,  %16, off offset:192 sc0 sc1\n\t"
    "global_load_dwordx4 %4,  %16, off offset:256 sc0 sc1\n\t"
    "global_load_dwordx4 %5,  %16, off offset:320 sc0 sc1\n\t"
    "global_load_dwordx4 %6,  %16, off offset:384 sc0 sc1\n\t"
    "global_load_dwordx4 %7,  %16, off offset:448 sc0 sc1\n\t"
    "global_load_dwordx4 %8,  %16, off offset:512 sc0 sc1\n\t"
    "global_load_dwordx4 %9,  %16, off offset:576 sc0 sc1\n\t"
    "global_load_dwordx4 %10, %16, off offset:640 sc0 sc1\n\t"
    "global_load_dwordx4 %11, %16, off offset:704 sc0 sc1\n\t"
    "global_load_dwordx4 %12, %16, off offset:768 sc0 sc1\n\t"
    "global_load_dwordx4 %13, %16, off offset:832 sc0 sc1\n\t"
    "global_load_dwordx4 %14, %16, off offset:896 sc0 sc1\n\t"
    "global_load_dwordx4 %15, %16, off offset:960 sc0 sc1\n\t"
    "s_waitcnt vmcnt(0)"
    : "=&v"(r[0]), "=&v"(r[1]), "=&v"(r[2]), "=&v"(r[3]),
      "=&v"(r[4]), "=&v"(r[5]), "=&v"(r[6]), "=&v"(r[7]),
      "=&v"(r[8]), "=&v"(r[9]), "=&v"(r[10]), "=&v"(r[11]),
      "=&v"(r[12]), "=&v"(r[13]), "=&v"(r[14]), "=&v"(r[15])
    : "v"(p)
    : "memory");
}
// issue-only variant (no waitcnt): overlap LLC latency with independent work.
// MUST be followed by drain_vm() + sched_barrier(0) before reading r[].
__device__ __forceinline__ void llc_issue_1k(const unsigned short* p, short8* r) {
  asm volatile(
    "global_load_dwordx4 %0,  %16, off sc0 sc1\n\t"
    "global_load_dwordx4 %1,  %16, off offset:64 sc0 sc1\n\t"
    "global_load_dwordx4 %2,  %16, off offset:128 sc0 sc1\n\t"
    "global_load_dwordx4 %3,  %16, off offset:192 sc0 sc1\n\t"
    "global_load_dwordx4 %4,  %16, off offset:256 sc0 sc1\n\t"
    "global_load_dwordx4 %5,  %16, off offset:320 sc0 sc1\n\t"
    "global_load_dwordx4 %6,  %16, off offset:384 sc0 sc1\n\t"
    "global_load_dwordx4 %7,  %16, off offset:448 sc0 sc1\n\t"
    "global_load_dwordx4 %8,  %16, off offset:512 sc0 sc1\n\t"
    "global_load_dwordx4 %9,  %16, off offset:576 sc0 sc1\n\t"
    "global_load_dwordx4 %10, %16, off offset:640 sc0 sc1\n\t"
    "global_load_dwordx4 %11, %16, off offset:704 sc0 sc1\n\t"
    "global_load_dwordx4 %12, %16, off offset:768 sc0 sc1\n\t"
    "global_load_dwordx4 %13, %16, off offset:832 sc0 sc1\n\t"
    "global_load_dwordx4 %14, %16, off offset:896 sc0 sc1\n\t"
    "global_load_dwordx4 %15, %16, off offset:960 sc0 sc1"
    : "=&v"(r[0]), "=&v"(r[1]), "=&v"(r[2]), "=&v"(r[3]),
      "=&v"(r[4]), "=&v"(r[5]), "=&v"(r[6]), "=&v"(r[7]),
      "=&v"(r[8]), "=&v"(r[9]), "=&v"(r[10]), "=&v"(r[11]),
      "=&v"(r[12]), "=&v"(r[13]), "=&v"(r[14]), "=&v"(r[15])
    : "v"(p)
    : "memory");
}
__device__ __forceinline__ void llc_store_4rows(unsigned short* p,
                                                unsigned short a, unsigned short b,
                                                unsigned short c, unsigned short d) {
  asm volatile(
    "global_store_short %4, %0, off sc0 sc1\n\t"
    "global_store_short %4, %1, off offset:1024 sc0 sc1\n\t"
    "global_store_short %4, %2, off offset:2048 sc0 sc1\n\t"
    "global_store_short %4, %3, off offset:3072 sc0 sc1"
    :: "v"((unsigned)a), "v"((unsigned)b), "v"((unsigned)c), "v"((unsigned)d), "v"(p)
    : "memory");
}
__device__ __forceinline__ int flag_ld_llc(const int* p) {
  int v; asm volatile("global_load_dword %0, %1, off sc0 sc1\n\ts_waitcnt vmcnt(0)"
                      : "=v"(v) : "v"(p) : "memory"); return v;
}
__device__ __forceinline__ void flag_st_llc(int* p, int v) {
  asm volatile("global_store_dword %0, %1, off sc0 sc1" :: "v"(p), "v"(v) : "memory");
}
__device__ __forceinline__ void drain_vm() {
  asm volatile("s_waitcnt vmcnt(0)" ::: "memory");
}

// ---------------- single fused prep kernel ----------------
// counters (16384 ints): aFlags bs*1024+hs*FSTR; bFlags 4096+...;
// probe flags at 8192+chain*1024+hs*FSTR. Zeroed by 64 blocks x 256.
#define PREP_BLOCKS 20048
__global__ __launch_bounds__(256) void prep_all(
    const float* __restrict__ x, const float* __restrict__ Wmih, const float* __restrict__ Wmhh,
    const float* __restrict__ Wih, const float* __restrict__ Whh,
    const float* __restrict__ b_d, const float* __restrict__ b_mih, const float* __restrict__ b_mhh,
    const float* __restrict__ b_ih, const float* __restrict__ b_hh,
    unsigned short* __restrict__ Xb, unsigned short* __restrict__ Wmih_b,
    unsigned short* __restrict__ Wmhh_b, unsigned short* __restrict__ W2,
    float* __restrict__ wd2, float* __restrict__ bA, float* __restrict__ bB,
    int* __restrict__ counters) {
  const int blk = blockIdx.x, tid = threadIdx.x;
  if (blk < 16384) {
    int i = blk * 256 + tid;
    float4 v = reinterpret_cast<const float4*>(x)[i];
    ushort4 o; o.x = f2bf(v.x); o.y = f2bf(v.y); o.z = f2bf(v.z); o.w = f2bf(v.w);
    reinterpret_cast<ushort4*>(Xb)[i] = o;
  } else if (blk < 17152) {
    int i = (blk - 16384) * 256 + tid;
    float4 v = reinterpret_cast<const float4*>(Wmih)[i];
    ushort4 o; o.x = f2bf(v.x); o.y = f2bf(v.y); o.z = f2bf(v.z); o.w = f2bf(v.w);
    reinterpret_cast<ushort4*>(Wmih_b)[i] = o;
  } else if (blk < 17920) {
    int i = (blk - 17152) * 256 + tid;
    float4 v = reinterpret_cast<const float4*>(Wmhh)[i];
    ushort4 o; o.x = f2bf(v.x); o.y = f2bf(v.y); o.z = f2bf(v.z); o.w = f2bf(v.w);
    reinterpret_cast<ushort4*>(Wmhh_b)[i] = o;
  } else if (blk < 19968) {
    int i4 = (blk - 17920) * 256 + tid;
    int i = i4 * 4; int n = i >> 10; int k = i & 1023;
    float4 v = (k < 512) ? reinterpret_cast<const float4*>(Wih + n * 512 + k)[0]
                         : reinterpret_cast<const float4*>(Whh + n * 512 + (k - 512))[0];
    ushort4 o; o.x = f2bf(v.x); o.y = f2bf(v.y); o.z = f2bf(v.z); o.w = f2bf(v.w);
    reinterpret_cast<ushort4*>(W2 + i)[0] = o;
  } else if (blk < 19984) {
    int t = (blk - 19968) * 256 + tid;
    if (t < 512) {
      float d = 0.5f * sigm(b_d[t]);
      float c = 1.0f;
      for (int i = 0; i < KHIST; ++i) {
        c *= ((float)i - d) / ((float)i + 1.0f);
        wd2[i * HDIM + t] = c;
      }
    } else if (t < 2048) {
      int n = t - 512;
      bA[n] = b_mih[n] + b_mhh[n];
    } else {
      int n = t - 2048;
      bB[n] = b_ih[n] + b_hh[n];
    }
  } else {
    int i = (blk - 19984) * 256 + tid;
    counters[i] = 0;
  }
}

// ---------------- input-projection GEMM: 128x128 tile, BK=32, dbuf LDS ----------------
__global__ __launch_bounds__(256) void gx_gemm_kernel(const unsigned short* __restrict__ Xb,
                                                      const unsigned short* __restrict__ Wb,
                                                      const float* __restrict__ bA,
                                                      unsigned short* __restrict__ GXh) {
  __shared__ unsigned short As[2][128 * 32];
  __shared__ unsigned short Bs[2][128 * 32];
  const int tid = threadIdx.x;
  const int lane = tid & 63;
  const int wv = tid >> 6;
  const int q = lane >> 4, r16 = lane & 15;
  const int wr = wv >> 1, wc = wv & 1;
  const int bid = (int)blockIdx.x;
  const int m0 = (bid & 255) * 128;
  const int n0 = (bid >> 8) * 128;

  const int sr0 = tid >> 2, sc0 = (tid & 3) * 8;
  const int sr1 = (256 + tid) >> 2, sc1 = (tid & 3) * 8;

  floatx4 acc[4][4];
  #pragma unroll
  for (int i = 0; i < 4; ++i)
    #pragma unroll
    for (int j = 0; j < 4; ++j) acc[i][j] = (floatx4){0.f, 0.f, 0.f, 0.f};

  {
    short8 a0 = *(const short8*)(Xb + (size_t)(m0 + sr0) * IDIM + sc0);
    short8 a1 = *(const short8*)(Xb + (size_t)(m0 + sr1) * IDIM + sc1);
    short8 b0 = *(const short8*)(Wb + (size_t)(n0 + sr0) * IDIM + sc0);
    short8 b1 = *(const short8*)(Wb + (size_t)(n0 + sr1) * IDIM + sc1);
    *(short8*)(As[0] + sr0 * 32 + sc0) = a0;
    *(short8*)(As[0] + sr1 * 32 + sc1) = a1;
    *(short8*)(Bs[0] + sr0 * 32 + sc0) = b0;
    *(short8*)(Bs[0] + sr1 * 32 + sc1) = b1;
  }

  for (int t = 0; t < 16; ++t) {
    const int cur = t & 1;
    __syncthreads();
    short8 a0, a1, b0, b1;
    if (t < 15) {
      int k0 = (t + 1) * 32;
      a0 = *(const short8*)(Xb + (size_t)(m0 + sr0) * IDIM + k0 + sc0);
      a1 = *(const short8*)(Xb + (size_t)(m0 + sr1) * IDIM + k0 + sc1);
      b0 = *(const short8*)(Wb + (size_t)(n0 + sr0) * IDIM + k0 + sc0);
      b1 = *(const short8*)(Wb + (size_t)(n0 + sr1) * IDIM + k0 + sc1);
    }
    short8 af[4], bf[4];
    #pragma unroll
    for (int i = 0; i < 4; ++i)
      af[i] = *(const short8*)(As[cur] + (wr * 64 + i * 16 + r16) * 32 + q * 8);
    #pragma unroll
    for (int j = 0; j < 4; ++j)
      bf[j] = *(const short8*)(Bs[cur] + (wc * 64 + j * 16 + r16) * 32 + q * 8);
    #pragma unroll
    for (int i = 0; i < 4; ++i)
      #pragma unroll
      for (int j = 0; j < 4; ++j)
        acc[i][j] = __builtin_amdgcn_mfma_f32_16x16x32_bf16(af[i], bf[j], acc[i][j], 0, 0, 0);
    if (t < 15) {
      *(short8*)(As[cur ^ 1] + sr0 * 32 + sc0) = a0;
      *(short8*)(As[cur ^ 1] + sr1 * 32 + sc1) = a1;
      *(short8*)(Bs[cur ^ 1] + sr0 * 32 + sc0) = b0;
      *(short8*)(Bs[cur ^ 1] + sr1 * 32 + sc1) = b1;
    }
  }

  #pragma unroll
  for (int j = 0; j < 4; ++j) {
    int col = n0 + wc * 64 + j * 16 + r16;
    float bias = bA[col];
    #pragma unroll
    for (int i = 0; i < 4; ++i) {
      #pragma unroll
      for (int jj = 0; jj < 4; ++jj) {
        int row = m0 + wr * 64 + i * 16 + q * 4 + jj;
        GXh[(size_t)row * 1536 + col] = f2bf(acc[i][j][jj] + bias);
      }
    }
  }
}

// ---------------- async persistent recurrent kernel ----------------
// r9 change vs r5/r8: per-wave self-gated polling. Each consumer wave polls
// exactly the flags it needs and issues its data load immediately on detect
// (no detect->barrier->wake->issue serialization through wv0). Ring-overwrite
// safety preserved: mid-barrier joins the slack-gate wave (A) / peer-poll
// waves (B) BEFORE the ring stores.
__global__ __launch_bounds__(512, 1) void recurrent2(
    const unsigned short* __restrict__ GXh,    // (T*256 x 1536) bf16
    const unsigned short* __restrict__ Wmhh,   // (1536 x 512) bf16 N-major
    const unsigned short* __restrict__ W2,     // (2048 x 1024) bf16 N-major
    const float* __restrict__ bB,              // (2048)
    const float* __restrict__ wd2,             // (32 x 512)
    unsigned short* __restrict__ h1his,        // (16 x 256 x 512) bf16
    unsigned short* __restrict__ h2his,        // (16 x 256 x 512) bf16
    float* __restrict__ sel,                   // (256 x 512) fp32
    const int* __restrict__ length,
    int* __restrict__ counters) {
  extern __shared__ char lds[];
  const int tid = threadIdx.x;
  const int lane = tid & 63;
  const int wv = tid >> 6;                 // 0..7
  const int q = lane >> 4, r16 = lane & 15;
  const int xcd = (int)blockIdx.x & 7;
  const int bs = xcd >> 1;
  const bool isA = (xcd & 1) == 0;
  const int hs = (int)blockIdx.x >> 3;
  const int hcol = hs * 16 + r16;
  int* aFlags = counters + bs * 1024;
  int* bFlags = counters + 4096 + bs * 1024;

  if (isA) {
    unsigned short* WA = (unsigned short*)lds;                        // [48][520]
    unsigned short* HI = (unsigned short*)(lds + 48 * WA_STRIDE * 2); // 64KB hist
    for (int idx = tid; idx < 48 * 64; idx += 512) {
      int rowi = idx >> 6, kc = idx & 63;
      int g = rowi >> 4, c = rowi & 15;
      const unsigned short* src = Wmhh + ((size_t)(g * 512 + hs * 16 + c)) * 512 + kc * 8;
      *(short8*)(WA + rowi * WA_STRIDE + kc * 8) = *(const short8*)src;
    }
    for (int idx = tid; idx < 4096; idx += 512)
      ((uint4*)HI)[idx] = (uint4){0, 0, 0, 0};
    float wdr[KHIST];
    #pragma unroll
    for (int l = 0; l < KHIST; ++l) wdr[l] = wd2[l * HDIM + hcol];
    __syncthreads();

    const int mi = wv & 3;
    const int m0 = bs * 64 + mi * 16;
    const int rg = mi * 4 + q;

    for (int s = 0; s < T_STEPS; ++s) {
      // GX prefetch (bf16 cached loads; complete during the poll)
      unsigned short gu[12];
      if (wv < 4) {
        #pragma unroll
        for (int j = 0; j < 4; ++j) {
          int row = m0 + q * 4 + j;
          size_t gidx = ((size_t)s * BATCH + row) * 1536 + hcol;
          gu[j]     = GXh[gidx];
          gu[4 + j] = GXh[gidx + 512];
          gu[8 + j] = GXh[gidx + 1024];
        }
      }
      // per-wave self-gated polls (no barrier between detect and data issue)
      if (wv < 4) {
        if (s > 0 && lane < 32) {
          const int* f = aFlags + lane * FSTR;
          while (flag_ld_llc(f) < s) __builtin_amdgcn_s_sleep(POLL_SLEEP);
        }
      } else if (wv == 4) {
        int tgt = s - (RDEPTH - 1);        // B slack gate (ring overwrite safety)
        if (tgt > 0 && lane < 32) {
          const int* f = bFlags + lane * FSTR;
          while (flag_ld_llc(f) < tgt) __builtin_amdgcn_s_sleep(POLL_SLEEP);
        }
      }
      float c1[4];
      unsigned short h1w[4];
      if (wv < 4) {
        short8 af[16];
        if (s > 0) {
          // issue h1 tile load immediately after this wave's own detect
          const unsigned short* ab = h1his +
              ((size_t)((s - 1) & (RDEPTH - 1)) * BATCH + m0 + r16) * 512 + q * 8;
          llc_issue_1k(ab, af);
        }
        // frac-diff filter (wave-private LDS rows) overlaps the load flight
        float f0 = 0.f, f1 = 0.f, f2 = 0.f, f3 = 0.f;
        #pragma unroll
        for (int jj = 1; jj <= KHIST; ++jj) {
          int sl = (s - jj) & (KHIST - 1);
          ushort4 hv = *(const ushort4*)(HI + ((size_t)(sl * 16 + rg) * 16 + r16) * 4);
          float wc = wdr[jj - 1];
          f0 += wc * bf2f(hv.x); f1 += wc * bf2f(hv.y);
          f2 += wc * bf2f(hv.z); f3 += wc * bf2f(hv.w);
        }
        float fj[4] = {f0, f1, f2, f3};
        floatx4 acc[3];
        #pragma unroll
        for (int g = 0; g < 3; ++g) acc[g] = (floatx4){0.f, 0.f, 0.f, 0.f};
        if (s > 0) {
          drain_vm();                               // af now valid
          __builtin_amdgcn_sched_barrier(0);        // rule #18: keep MFMA below
          #pragma unroll
          for (int kk = 0; kk < 16; ++kk) {
            #pragma unroll
            for (int g = 0; g < 3; ++g) {
              short8 b = *(const short8*)(WA + (size_t)(g * 16 + r16) * WA_STRIDE + kk * 32 + q * 8);
              acc[g] = __builtin_amdgcn_mfma_f32_16x16x32_bf16(af[kk], b, acc[g], 0, 0, 0);
            }
          }
        }
        #pragma unroll
        for (int j = 0; j < 4; ++j) {
          float gI = bf2f(gu[j])     + acc[0][j];
          float gO = bf2f(gu[4 + j]) + acc[1][j];
          float gG = bf2f(gu[8 + j]) + acc[2][j];
          float ig = sigm(gI), og = sigm(gO), cd = tanh_f(gG);
          float c1v = ig * cd - fj[j];
          c1[j] = c1v;
          h1w[j] = f2bf(og * tanh_f(c1v));
        }
      }
      __syncthreads();     // mid: joins wv4 slack-gate before ring overwrite
      if (wv < 4) {
        llc_store_4rows(h1his + ((size_t)(s & (RDEPTH - 1)) * BATCH + m0 + q * 4) * 512 + hcol,
                        h1w[0], h1w[1], h1w[2], h1w[3]);
        ushort4 hw;
        hw.x = f2bf(c1[0]); hw.y = f2bf(c1[1]); hw.z = f2bf(c1[2]); hw.w = f2bf(c1[3]);
        *(ushort4*)(HI + ((size_t)((s & (KHIST - 1)) * 16 + rg) * 16 + r16) * 4) = hw;
      }
      drain_vm();
      __syncthreads();
      if (tid == 0)
        flag_st_llc(aFlags + hs * FSTR, s + 1);
    }
  } else {
    // ---- B block ----
    unsigned short* WB = (unsigned short*)lds;                 // [64][1032]
    float* EX = (float*)(lds + 64 * WB_STRIDE * 2);            // exch [4 mi][4 g][64 lane][4]
    for (int idx = tid; idx < 64 * 128; idx += 512) {
      int rowi = idx >> 7, kc = idx & 127;
      int g = rowi >> 4, c = rowi & 15;
      const unsigned short* src = W2 + ((size_t)(g * 512 + hs * 16 + c)) * 1024 + kc * 8;
      *(short8*)(WB + rowi * WB_STRIDE + kc * 8) = *(const short8*)src;
    }
    const int mi = wv >> 1, kh = wv & 1;
    const int m0 = bs * 64 + mi * 16;
    float c2r[4] = {0.f, 0.f, 0.f, 0.f};
    int lenr[4];
    float bBr[4];
    #pragma unroll
    for (int j = 0; j < 4; ++j) lenr[j] = length[m0 + q * 4 + j];
    #pragma unroll
    for (int g = 0; g < 4; ++g) bBr[g] = bB[g * 512 + hcol];
    __syncthreads();

    for (int t = 0; t < T_STEPS; ++t) {
      // per-wave self-gated polls: kh=0 needs A done t; kh=1 needs B peers done t-1
      if (kh == 0) {
        if (lane < 32) {
          const int* f = aFlags + lane * FSTR;
          while (flag_ld_llc(f) < t + 1) __builtin_amdgcn_s_sleep(POLL_SLEEP);
        }
      } else {
        if (t > 0 && lane < 32) {
          const int* f = bFlags + lane * FSTR;
          while (flag_ld_llc(f) < t) __builtin_amdgcn_s_sleep(POLL_SLEEP);
        }
      }
      floatx4 acc[4];
      #pragma unroll
      for (int g = 0; g < 4; ++g) acc[g] = (floatx4){0.f, 0.f, 0.f, 0.f};
      bool doit = !(kh == 1 && t == 0);
      if (doit) {
        const unsigned short* ab;
        if (kh == 0)
          ab = h1his + ((size_t)(t & (RDEPTH - 1)) * BATCH + m0 + r16) * 512 + q * 8;
        else
          ab = h2his + ((size_t)((t - 1) & (RDEPTH - 1)) * BATCH + m0 + r16) * 512 + q * 8;
        short8 af[16];
        llc_load_1k(ab, af);
        #pragma unroll
        for (int kk = 0; kk < 16; ++kk) {
          #pragma unroll
          for (int g = 0; g < 4; ++g) {
            short8 b = *(const short8*)(WB + (size_t)(g * 16 + r16) * WB_STRIDE + kh * 512 + kk * 32 + q * 8);
            acc[g] = __builtin_amdgcn_mfma_f32_16x16x32_bf16(af[kk], b, acc[g], 0, 0, 0);
          }
        }
      }
      if (kh == 1) {
        #pragma unroll
        for (int g = 0; g < 4; ++g)
          *(floatx4*)(EX + ((size_t)(mi * 4 + g) * 64 + lane) * 4) = acc[g];
      }
      __syncthreads();   // mid: EX handoff + peer-poll gate before h2 ring store
      if (kh == 0) {
        #pragma unroll
        for (int g = 0; g < 4; ++g)
          acc[g] += *(const floatx4*)(EX + ((size_t)(mi * 4 + g) * 64 + lane) * 4);
        unsigned short h2w[4];
        #pragma unroll
        for (int j = 0; j < 4; ++j) {
          int row = m0 + q * 4 + j;
          float gi = acc[0][j] + bBr[0];
          float gf = acc[1][j] + bBr[1];
          float gg = acc[2][j] + bBr[2];
          float go = acc[3][j] + bBr[3];
          float c2n = sigm(gf) * c2r[j] + sigm(gi) * tanh_f(gg);
          c2r[j] = c2n;
          float h2n = tanh_f(sigm(go) * tanh_f(c2n));
          h2w[j] = f2bf(h2n);
          if (lenr[j] == t) sel[(size_t)row * 512 + hcol] = h2n;
        }
        llc_store_4rows(h2his + ((size_t)(t & (RDEPTH - 1)) * BATCH + m0 + q * 4) * 512 + hcol,
                        h2w[0], h2w[1], h2w[2], h2w[3]);
      }
      drain_vm();
      __syncthreads();
      if (tid == 0)
        flag_st_llc(bFlags + hs * FSTR, t + 1);
    }
  }
}

// ---------------- pure-handshake probe (diagnostic) ----------------
// 128 blocks = 4 chains x 32 slices, 1 wave each. Exact r5 flag protocol:
// poll all 32 peer flags -> converge -> publish. No data, no compute, idle
// GPU. Duration / PROBE_STEPS = intrinsic lockstep handshake cost.
__global__ __launch_bounds__(64) void sync_probe(int* __restrict__ counters) {
  const int lane = threadIdx.x;
  const int chain = (int)blockIdx.x & 3;
  const int hs = (int)blockIdx.x >> 2;
  int* flags = counters + 8192 + chain * 1024;
  for (int s = 0; s < PROBE_STEPS; ++s) {
    if (lane < 32 && s > 0) {
      const int* f = flags + lane * FSTR;
      while (flag_ld_llc(f) < s) __builtin_amdgcn_s_sleep(POLL_SLEEP);
    }
    __syncthreads();
    if (lane == 0)
      flag_st_llc(flags + hs * FSTR, s + 1);
  }
}

// ---------------- output head ----------------
__global__ void out_head_kernel(const float* __restrict__ sel, const float* __restrict__ Wout,
                                const float* __restrict__ bout, float* __restrict__ out) {
  int b = blockIdx.x, lane = threadIdx.x;   // 256 blocks x 64 threads
  float acc[5] = {0.f, 0.f, 0.f, 0.f, 0.f};
  for (int j = lane; j < HDIM; j += 64) {
    float x = sel[(size_t)b * HDIM + j];
    #pragma unroll
    for (int o = 0; o < 5; ++o) acc[o] += x * Wout[o * HDIM + j];
  }
  #pragma unroll
  for (int o = 0; o < 5; ++o)
    for (int off = 32; off > 0; off >>= 1) acc[o] += __shfl_down(acc[o], off);
  if (lane == 0) {
    float v[5]; float m = -1e30f;
    #pragma unroll
    for (int o = 0; o < 5; ++o) { v[o] = acc[o] + bout[o]; m = fmaxf(m, v[o]); }
    float s = 0.f;
    #pragma unroll
    for (int o = 0; o < 5; ++o) s += __expf(v[o] - m);
    float l = logf(s) + m;
    #pragma unroll
    for (int o = 0; o < 5; ++o) out[b * 5 + o] = v[o] - l;
  }
}

// ---------------- launch ----------------
extern "C" void kernel_launch(void* const* d_in, const int* in_sizes, int n_in,
                              void* d_out, int out_size, void* d_ws, size_t ws_size,
                              hipStream_t stream) {
  const float* x      = (const float*)d_in[0];
  const int*   length = (const int*)d_in[1];
  const float* b_d    = (const float*)d_in[2];
  const float* W_mih  = (const float*)d_in[3];
  const float* W_mhh  = (const float*)d_in[4];
  const float* b_mih  = (const float*)d_in[5];
  const float* b_mhh  = (const float*)d_in[6];
  const float* W_ih   = (const float*)d_in[7];
  const float* W_hh   = (const float*)d_in[8];
  const float* b_ih   = (const float*)d_in[9];
  const float* b_hh   = (const float*)d_in[10];
  const float* W_out  = (const float*)d_in[11];
  const float* b_out  = (const float*)d_in[12];
  float* out = (float*)d_out;

  char* ws = (char*)d_ws;
  size_t off = 0;
  auto take = [&](size_t bytes) -> char* {
    char* p = ws + off;
    off += (bytes + 255) & ~(size_t)255;
    return p;
  };

  unsigned short* Xb     = (unsigned short*)take((size_t)T_STEPS * BATCH * IDIM * 2);
  unsigned short* Wmih_b = (unsigned short*)take(1536 * 512 * 2);
  unsigned short* Wmhh_b = (unsigned short*)take(1536 * 512 * 2);
  unsigned short* W2_b   = (unsigned short*)take(2048 * 1024 * 2);
  float* bA  = (float*)take(1536 * 4);
  float* bB  = (float*)take(2048 * 4);
  float* wd2 = (float*)take(KHIST * HDIM * 4);
  unsigned short* h1his = (unsigned short*)take((size_t)RDEPTH * BATCH * 512 * 2);
  unsigned short* h2his = (unsigned short*)take((size_t)RDEPTH * BATCH * 512 * 2);
  float* sel = (float*)take((size_t)BATCH * HDIM * 4);
  int* counters = (int*)take(65536);
  unsigned short* GXh = (unsigned short*)take((size_t)T_STEPS * BATCH * 1536 * 2);
  if (off > ws_size) return;  // workspace too small -> loud validation failure

  prep_all<<<PREP_BLOCKS, 256, 0, stream>>>(x, W_mih, W_mhh, W_ih, W_hh,
                                            b_d, b_mih, b_mhh, b_ih, b_hh,
                                            Xb, Wmih_b, Wmhh_b, W2_b, wd2, bA, bB, counters);
  // 128x128 tiles: (32768/128) * (1536/128) = 256 * 12 = 3072 blocks, bn-outer
  gx_gemm_kernel<<<3072, 256, 0, stream>>>(Xb, Wmih_b, bA, GXh);

  hipFuncSetAttribute((const void*)recurrent2, hipFuncAttributeMaxDynamicSharedMemorySize, LDS_BYTES);
  void* kargs[] = { (void*)&GXh, (void*)&Wmhh_b, (void*)&W2_b, (void*)&bB, (void*)&wd2,
                    (void*)&h1his, (void*)&h2his, (void*)&sel, (void*)&length,
                    (void*)&counters };
  hipLaunchCooperativeKernel((void*)recurrent2, dim3(256), dim3(512), kargs, LDS_BYTES, stream);

  out_head_kernel<<<BATCH, 64, 0, stream>>>(sel, W_out, b_out, out);

  // diagnostic: pure-handshake probe on idle GPU (duration = total - rest)
  sync_probe<<<128, 64, 0, stream>>>(counters);
}

// Round 10
// 1266.559 us; speedup vs baseline: 1.2128x; 1.2128x over previous
//
#include <hip/hip_runtime.h>
#include <hip/hip_cooperative_groups.h>
#include <cstdint>
#include <cstddef>

typedef __attribute__((ext_vector_type(8))) short short8;   // 8 bf16 (4 VGPRs) MFMA frag
typedef __attribute__((ext_vector_type(4))) float floatx4;  // MFMA accumulator

#define T_STEPS 128
#define BATCH   256
#define IDIM    512
#define HDIM    512
#define KHIST   32
#define RDEPTH  16

// LDS layout (recurrent2)
#define WA_STRIDE 520      // 512 + 8 pad
#define WB_STRIDE 1032     // 1024 + 8 pad
#define LDS_BYTES 148480   // B: WB 64*1032*2 + EX 16384; A: 49920 + 65536

// flags: one per 128B LLC line (FSTR ints apart)
#define FSTR 32
#define POLL_SLEEP 8

__device__ __forceinline__ unsigned short f2bf(float x) {
  union { float f; unsigned u; } v; v.f = x;
  unsigned r = v.u + 0x7fffu + ((v.u >> 16) & 1u);   // RNE
  return (unsigned short)(r >> 16);
}
__device__ __forceinline__ float bf2f(unsigned short s) {
  union { unsigned u; float f; } v; v.u = ((unsigned)s) << 16; return v.f;
}
__device__ __forceinline__ float sigm(float x) { return 1.0f / (1.0f + __expf(-x)); }
__device__ __forceinline__ float tanh_f(float x) {
  float ax = fabsf(x);
  float e = __expf(-2.0f * ax);
  float t = (1.0f - e) / (1.0f + e);
  return x < 0.0f ? -t : t;
}

// ---- coherent exchange primitives ----
// sc0 sc1 : LLC scope (r6-proven) — cross-XCD edges + ALL flags.
// sc0     : L2 scope — same-XCD producer->consumer (write-back L2 is the
//           coherence point within an XCD; sc0 bypasses L1 only). Used ONLY
//           for data whose producer+consumers share an XCD under the
//           blockIdx&7 placement. Wrong placement/semantics => stale VALUES
//           => loud absmax fail. Flags never use sc0-only => no hang path.
__device__ __forceinline__ void llc_load_1k(const unsigned short* p, short8* r) {
  asm volatile(
    "global_load_dwordx4 %0,  %16, off sc0 sc1\n\t"
    "global_load_dwordx4 %1,  %16, off offset:64 sc0 sc1\n\t"
    "global_load_dwordx4 %2,  %16, off offset:128 sc0 sc1\n\t"
    "global_load_dwordx4 %3,  %16, off offset:192 sc0 sc1\n\t"
    "global_load_dwordx4 %4,  %16, off offset:256 sc0 sc1\n\t"
    "global_load_dwordx4 %5,  %16, off offset:320 sc0 sc1\n\t"
    "global_load_dwordx4 %6,  %16, off offset:384 sc0 sc1\n\t"
    "global_load_dwordx4 %7,  %16, off offset:448 sc0 sc1\n\t"
    "global_load_dwordx4 %8,  %16, off offset:512 sc0 sc1\n\t"
    "global_load_dwordx4 %9,  %16, off offset:576 sc0 sc1\n\t"
    "global_load_dwordx4 %10, %16, off offset:640 sc0 sc1\n\t"
    "global_load_dwordx4 %11, %16, off offset:704 sc0 sc1\n\t"
    "global_load_dwordx4 %12, %16, off offset:768 sc0 sc1\n\t"
    "global_load_dwordx4 %13, %16, off offset:832 sc0 sc1\n\t"
    "global_load_dwordx4 %14, %16, off offset:896 sc0 sc1\n\t"
    "global_load_dwordx4 %15, %16, off offset:960 sc0 sc1\n\t"
    "s_waitcnt vmcnt(0)"
    : "=&v"(r[0]), "=&v"(r[1]), "=&v"(r[2]), "=&v"(r[3]),
      "=&v"(r[4]), "=&v"(r[5]), "=&v"(r[6]), "=&v"(r[7]),
      "=&v"(r[8]), "=&v"(r[9]), "=&v"(r[10]), "=&v"(r[11]),
      "=&v"(r[12]), "=&v"(r[13]), "=&v"(r[14]), "=&v"(r[15])
    : "v"(p)
    : "memory");
}
// same-XCD blocking load: sc0 only (L2-hit path)
__device__ __forceinline__ void l2_load_1k(const unsigned short* p, short8* r) {
  asm volatile(
    "global_load_dwordx4 %0,  %16, off sc0\n\t"
    "global_load_dwordx4 %1,  %16, off offset:64 sc0\n\t"
    "global_load_dwordx4 %2,  %16, off offset:128 sc0\n\t"
    "global_load_dwordx4 %3,  %16, off offset:192 sc0\n\t"
    "global_load_dwordx4 %4,  %16, off offset:256 sc0\n\t"
    "global_load_dwordx4 %5,  %16, off offset:320 sc0\n\t"
    "global_load_dwordx4 %6,  %16, off offset:384 sc0\n\t"
    "global_load_dwordx4 %7,  %16, off offset:448 sc0\n\t"
    "global_load_dwordx4 %8,  %16, off offset:512 sc0\n\t"
    "global_load_dwordx4 %9,  %16, off offset:576 sc0\n\t"
    "global_load_dwordx4 %10, %16, off offset:640 sc0\n\t"
    "global_load_dwordx4 %11, %16, off offset:704 sc0\n\t"
    "global_load_dwordx4 %12, %16, off offset:768 sc0\n\t"
    "global_load_dwordx4 %13, %16, off offset:832 sc0\n\t"
    "global_load_dwordx4 %14, %16, off offset:896 sc0\n\t"
    "global_load_dwordx4 %15, %16, off offset:960 sc0\n\t"
    "s_waitcnt vmcnt(0)"
    : "=&v"(r[0]), "=&v"(r[1]), "=&v"(r[2]), "=&v"(r[3]),
      "=&v"(r[4]), "=&v"(r[5]), "=&v"(r[6]), "=&v"(r[7]),
      "=&v"(r[8]), "=&v"(r[9]), "=&v"(r[10]), "=&v"(r[11]),
      "=&v"(r[12]), "=&v"(r[13]), "=&v"(r[14]), "=&v"(r[15])
    : "v"(p)
    : "memory");
}
// same-XCD issue-only (no waitcnt): overlap L2 latency with independent work.
// MUST be followed by drain_vm() + sched_barrier(0) before reading r[].
__device__ __forceinline__ void l2_issue_1k(const unsigned short* p, short8* r) {
  asm volatile(
    "global_load_dwordx4 %0,  %16, off sc0\n\t"
    "global_load_dwordx4 %1,  %16, off offset:64 sc0\n\t"
    "global_load_dwordx4 %2,  %16, off offset:128 sc0\n\t"
    "global_load_dwordx4 %3,  %16, off offset:192 sc0\n\t"
    "global_load_dwordx4 %4,  %16, off offset:256 sc0\n\t"
    "global_load_dwordx4 %5,  %16, off offset:320 sc0\n\t"
    "global_load_dwordx4 %6,  %16, off offset:384 sc0\n\t"
    "global_load_dwordx4 %7,  %16, off offset:448 sc0\n\t"
    "global_load_dwordx4 %8,  %16, off offset:512 sc0\n\t"
    "global_load_dwordx4 %9,  %16, off offset:576 sc0\n\t"
    "global_load_dwordx4 %10, %16, off offset:640 sc0\n\t"
    "global_load_dwordx4 %11, %16, off offset:704 sc0\n\t"
    "global_load_dwordx4 %12, %16, off offset:768 sc0\n\t"
    "global_load_dwordx4 %13, %16, off offset:832 sc0\n\t"
    "global_load_dwordx4 %14, %16, off offset:896 sc0\n\t"
    "global_load_dwordx4 %15, %16, off offset:960 sc0"
    : "=&v"(r[0]), "=&v"(r[1]), "=&v"(r[2]), "=&v"(r[3]),
      "=&v"(r[4]), "=&v"(r[5]), "=&v"(r[6]), "=&v"(r[7]),
      "=&v"(r[8]), "=&v"(r[9]), "=&v"(r[10]), "=&v"(r[11]),
      "=&v"(r[12]), "=&v"(r[13]), "=&v"(r[14]), "=&v"(r[15])
    : "v"(p)
    : "memory");
}
__device__ __forceinline__ void llc_store_4rows(unsigned short* p,
                                                unsigned short a, unsigned short b,
                                                unsigned short c, unsigned short d) {
  asm volatile(
    "global_store_short %4, %0, off sc0 sc1\n\t"
    "global_store_short %4, %1, off offset:1024 sc0 sc1\n\t"
    "global_store_short %4, %2, off offset:2048 sc0 sc1\n\t"
    "global_store_short %4, %3, off offset:3072 sc0 sc1"
    :: "v"((unsigned)a), "v"((unsigned)b), "v"((unsigned)c), "v"((unsigned)d), "v"(p)
    : "memory");
}
__device__ __forceinline__ void l2_store_4rows(unsigned short* p,
                                               unsigned short a, unsigned short b,
                                               unsigned short c, unsigned short d) {
  asm volatile(
    "global_store_short %4, %0, off sc0\n\t"
    "global_store_short %4, %1, off offset:1024 sc0\n\t"
    "global_store_short %4, %2, off offset:2048 sc0\n\t"
    "global_store_short %4, %3, off offset:3072 sc0"
    :: "v"((unsigned)a), "v"((unsigned)b), "v"((unsigned)c), "v"((unsigned)d), "v"(p)
    : "memory");
}
__device__ __forceinline__ int flag_ld_llc(const int* p) {
  int v; asm volatile("global_load_dword %0, %1, off sc0 sc1\n\ts_waitcnt vmcnt(0)"
                      : "=v"(v) : "v"(p) : "memory"); return v;
}
__device__ __forceinline__ void flag_st_llc(int* p, int v) {
  asm volatile("global_store_dword %0, %1, off sc0 sc1" :: "v"(p), "v"(v) : "memory");
}
__device__ __forceinline__ void drain_vm() {
  asm volatile("s_waitcnt vmcnt(0)" ::: "memory");
}

// ---------------- single fused prep kernel ----------------
// counters: aFlags at bs*1024 + hs*FSTR; bFlags at 4096 + bs*1024 + hs*FSTR.
// 8192 ints total -> zero with 32 blocks x 256.
#define PREP_BLOCKS 20016
__global__ __launch_bounds__(256) void prep_all(
    const float* __restrict__ x, const float* __restrict__ Wmih, const float* __restrict__ Wmhh,
    const float* __restrict__ Wih, const float* __restrict__ Whh,
    const float* __restrict__ b_d, const float* __restrict__ b_mih, const float* __restrict__ b_mhh,
    const float* __restrict__ b_ih, const float* __restrict__ b_hh,
    unsigned short* __restrict__ Xb, unsigned short* __restrict__ Wmih_b,
    unsigned short* __restrict__ Wmhh_b, unsigned short* __restrict__ W2,
    float* __restrict__ wd2, float* __restrict__ bA, float* __restrict__ bB,
    int* __restrict__ counters) {
  const int blk = blockIdx.x, tid = threadIdx.x;
  if (blk < 16384) {
    int i = blk * 256 + tid;
    float4 v = reinterpret_cast<const float4*>(x)[i];
    ushort4 o; o.x = f2bf(v.x); o.y = f2bf(v.y); o.z = f2bf(v.z); o.w = f2bf(v.w);
    reinterpret_cast<ushort4*>(Xb)[i] = o;
  } else if (blk < 17152) {
    int i = (blk - 16384) * 256 + tid;
    float4 v = reinterpret_cast<const float4*>(Wmih)[i];
    ushort4 o; o.x = f2bf(v.x); o.y = f2bf(v.y); o.z = f2bf(v.z); o.w = f2bf(v.w);
    reinterpret_cast<ushort4*>(Wmih_b)[i] = o;
  } else if (blk < 17920) {
    int i = (blk - 17152) * 256 + tid;
    float4 v = reinterpret_cast<const float4*>(Wmhh)[i];
    ushort4 o; o.x = f2bf(v.x); o.y = f2bf(v.y); o.z = f2bf(v.z); o.w = f2bf(v.w);
    reinterpret_cast<ushort4*>(Wmhh_b)[i] = o;
  } else if (blk < 19968) {
    int i4 = (blk - 17920) * 256 + tid;
    int i = i4 * 4; int n = i >> 10; int k = i & 1023;
    float4 v = (k < 512) ? reinterpret_cast<const float4*>(Wih + n * 512 + k)[0]
                         : reinterpret_cast<const float4*>(Whh + n * 512 + (k - 512))[0];
    ushort4 o; o.x = f2bf(v.x); o.y = f2bf(v.y); o.z = f2bf(v.z); o.w = f2bf(v.w);
    reinterpret_cast<ushort4*>(W2 + i)[0] = o;
  } else if (blk < 19984) {
    int t = (blk - 19968) * 256 + tid;
    if (t < 512) {
      float d = 0.5f * sigm(b_d[t]);
      float c = 1.0f;
      for (int i = 0; i < KHIST; ++i) {
        c *= ((float)i - d) / ((float)i + 1.0f);
        wd2[i * HDIM + t] = c;
      }
    } else if (t < 2048) {
      int n = t - 512;
      bA[n] = b_mih[n] + b_mhh[n];
    } else {
      int n = t - 2048;
      bB[n] = b_ih[n] + b_hh[n];
    }
  } else {
    int i = (blk - 19984) * 256 + tid;
    counters[i] = 0;
  }
}

// ---------------- input-projection GEMM: 128x128 tile, BK=32, dbuf LDS ----------------
__global__ __launch_bounds__(256) void gx_gemm_kernel(const unsigned short* __restrict__ Xb,
                                                      const unsigned short* __restrict__ Wb,
                                                      const float* __restrict__ bA,
                                                      unsigned short* __restrict__ GXh) {
  __shared__ unsigned short As[2][128 * 32];
  __shared__ unsigned short Bs[2][128 * 32];
  const int tid = threadIdx.x;
  const int lane = tid & 63;
  const int wv = tid >> 6;
  const int q = lane >> 4, r16 = lane & 15;
  const int wr = wv >> 1, wc = wv & 1;
  const int bid = (int)blockIdx.x;
  const int m0 = (bid & 255) * 128;
  const int n0 = (bid >> 8) * 128;

  const int sr0 = tid >> 2, sc0 = (tid & 3) * 8;
  const int sr1 = (256 + tid) >> 2, sc1 = (tid & 3) * 8;

  floatx4 acc[4][4];
  #pragma unroll
  for (int i = 0; i < 4; ++i)
    #pragma unroll
    for (int j = 0; j < 4; ++j) acc[i][j] = (floatx4){0.f, 0.f, 0.f, 0.f};

  {
    short8 a0 = *(const short8*)(Xb + (size_t)(m0 + sr0) * IDIM + sc0);
    short8 a1 = *(const short8*)(Xb + (size_t)(m0 + sr1) * IDIM + sc1);
    short8 b0 = *(const short8*)(Wb + (size_t)(n0 + sr0) * IDIM + sc0);
    short8 b1 = *(const short8*)(Wb + (size_t)(n0 + sr1) * IDIM + sc1);
    *(short8*)(As[0] + sr0 * 32 + sc0) = a0;
    *(short8*)(As[0] + sr1 * 32 + sc1) = a1;
    *(short8*)(Bs[0] + sr0 * 32 + sc0) = b0;
    *(short8*)(Bs[0] + sr1 * 32 + sc1) = b1;
  }

  for (int t = 0; t < 16; ++t) {
    const int cur = t & 1;
    __syncthreads();
    short8 a0, a1, b0, b1;
    if (t < 15) {
      int k0 = (t + 1) * 32;
      a0 = *(const short8*)(Xb + (size_t)(m0 + sr0) * IDIM + k0 + sc0);
      a1 = *(const short8*)(Xb + (size_t)(m0 + sr1) * IDIM + k0 + sc1);
      b0 = *(const short8*)(Wb + (size_t)(n0 + sr0) * IDIM + k0 + sc0);
      b1 = *(const short8*)(Wb + (size_t)(n0 + sr1) * IDIM + k0 + sc1);
    }
    short8 af[4], bf[4];
    #pragma unroll
    for (int i = 0; i < 4; ++i)
      af[i] = *(const short8*)(As[cur] + (wr * 64 + i * 16 + r16) * 32 + q * 8);
    #pragma unroll
    for (int j = 0; j < 4; ++j)
      bf[j] = *(const short8*)(Bs[cur] + (wc * 64 + j * 16 + r16) * 32 + q * 8);
    #pragma unroll
    for (int i = 0; i < 4; ++i)
      #pragma unroll
      for (int j = 0; j < 4; ++j)
        acc[i][j] = __builtin_amdgcn_mfma_f32_16x16x32_bf16(af[i], bf[j], acc[i][j], 0, 0, 0);
    if (t < 15) {
      *(short8*)(As[cur ^ 1] + sr0 * 32 + sc0) = a0;
      *(short8*)(As[cur ^ 1] + sr1 * 32 + sc1) = a1;
      *(short8*)(Bs[cur ^ 1] + sr0 * 32 + sc0) = b0;
      *(short8*)(Bs[cur ^ 1] + sr1 * 32 + sc1) = b1;
    }
  }

  #pragma unroll
  for (int j = 0; j < 4; ++j) {
    int col = n0 + wc * 64 + j * 16 + r16;
    float bias = bA[col];
    #pragma unroll
    for (int i = 0; i < 4; ++i) {
      #pragma unroll
      for (int jj = 0; jj < 4; ++jj) {
        int row = m0 + wr * 64 + i * 16 + q * 4 + jj;
        GXh[(size_t)row * 1536 + col] = f2bf(acc[i][j][jj] + bias);
      }
    }
  }
}

// ---------------- async persistent recurrent kernel ----------------
// r10 change vs r9: dual-store exchange. Same-XCD broadcasts (A-peer h1,
// B-peer h2) go through the XCD's write-back L2 (sc0 store + sc0 load);
// the one cross-XCD edge (A->B h1) keeps a separate sc0sc1 LLC copy.
// All flags stay sc0 sc1 (liveness proven). Cuts per-step LLC reads
// 24MB -> 8MB (the measured dominant term; handshake idle = 0.95us/step).
__global__ __launch_bounds__(512, 1) void recurrent2(
    const unsigned short* __restrict__ GXh,    // (T*256 x 1536) bf16
    const unsigned short* __restrict__ Wmhh,   // (1536 x 512) bf16 N-major
    const unsigned short* __restrict__ W2,     // (2048 x 1024) bf16 N-major
    const float* __restrict__ bB,              // (2048)
    const float* __restrict__ wd2,             // (32 x 512)
    unsigned short* __restrict__ h1L2,         // (16 x 256 x 512) bf16, A-XCD L2 copy
    unsigned short* __restrict__ h1LLC,        // (16 x 256 x 512) bf16, LLC copy for B
    unsigned short* __restrict__ h2his,        // (16 x 256 x 512) bf16, B-XCD L2
    float* __restrict__ sel,                   // (256 x 512) fp32
    const int* __restrict__ length,
    int* __restrict__ counters) {
  extern __shared__ char lds[];
  const int tid = threadIdx.x;
  const int lane = tid & 63;
  const int wv = tid >> 6;                 // 0..7
  const int q = lane >> 4, r16 = lane & 15;
  const int xcd = (int)blockIdx.x & 7;
  const int bs = xcd >> 1;
  const bool isA = (xcd & 1) == 0;
  const int hs = (int)blockIdx.x >> 3;
  const int hcol = hs * 16 + r16;
  int* aFlags = counters + bs * 1024;
  int* bFlags = counters + 4096 + bs * 1024;

  if (isA) {
    unsigned short* WA = (unsigned short*)lds;                        // [48][520]
    unsigned short* HI = (unsigned short*)(lds + 48 * WA_STRIDE * 2); // 64KB hist
    for (int idx = tid; idx < 48 * 64; idx += 512) {
      int rowi = idx >> 6, kc = idx & 63;
      int g = rowi >> 4, c = rowi & 15;
      const unsigned short* src = Wmhh + ((size_t)(g * 512 + hs * 16 + c)) * 512 + kc * 8;
      *(short8*)(WA + rowi * WA_STRIDE + kc * 8) = *(const short8*)src;
    }
    for (int idx = tid; idx < 4096; idx += 512)
      ((uint4*)HI)[idx] = (uint4){0, 0, 0, 0};
    float wdr[KHIST];
    #pragma unroll
    for (int l = 0; l < KHIST; ++l) wdr[l] = wd2[l * HDIM + hcol];
    __syncthreads();

    const int mi = wv & 3;
    const int m0 = bs * 64 + mi * 16;
    const int rg = mi * 4 + q;

    for (int s = 0; s < T_STEPS; ++s) {
      // GX prefetch (bf16 cached loads; complete during the poll)
      unsigned short gu[12];
      if (wv < 4) {
        #pragma unroll
        for (int j = 0; j < 4; ++j) {
          int row = m0 + q * 4 + j;
          size_t gidx = ((size_t)s * BATCH + row) * 1536 + hcol;
          gu[j]     = GXh[gidx];
          gu[4 + j] = GXh[gidx + 512];
          gu[8 + j] = GXh[gidx + 1024];
        }
      }
      // per-wave self-gated polls (no barrier between detect and data issue)
      if (wv < 4) {
        if (s > 0 && lane < 32) {
          const int* f = aFlags + lane * FSTR;
          while (flag_ld_llc(f) < s) __builtin_amdgcn_s_sleep(POLL_SLEEP);
        }
      } else if (wv == 4) {
        int tgt = s - (RDEPTH - 1);        // B slack gate (ring overwrite safety)
        if (tgt > 0 && lane < 32) {
          const int* f = bFlags + lane * FSTR;
          while (flag_ld_llc(f) < tgt) __builtin_amdgcn_s_sleep(POLL_SLEEP);
        }
      }
      float c1[4];
      unsigned short h1w[4];
      if (wv < 4) {
        short8 af[16];
        if (s > 0) {
          // issue h1 tile load (same-XCD L2 copy) right after own detect
          const unsigned short* ab = h1L2 +
              ((size_t)((s - 1) & (RDEPTH - 1)) * BATCH + m0 + r16) * 512 + q * 8;
          l2_issue_1k(ab, af);
        }
        // frac-diff filter (wave-private LDS rows) overlaps the load flight
        float f0 = 0.f, f1 = 0.f, f2 = 0.f, f3 = 0.f;
        #pragma unroll
        for (int jj = 1; jj <= KHIST; ++jj) {
          int sl = (s - jj) & (KHIST - 1);
          ushort4 hv = *(const ushort4*)(HI + ((size_t)(sl * 16 + rg) * 16 + r16) * 4);
          float wc = wdr[jj - 1];
          f0 += wc * bf2f(hv.x); f1 += wc * bf2f(hv.y);
          f2 += wc * bf2f(hv.z); f3 += wc * bf2f(hv.w);
        }
        float fj[4] = {f0, f1, f2, f3};
        floatx4 acc[3];
        #pragma unroll
        for (int g = 0; g < 3; ++g) acc[g] = (floatx4){0.f, 0.f, 0.f, 0.f};
        if (s > 0) {
          drain_vm();                               // af now valid
          __builtin_amdgcn_sched_barrier(0);        // rule #18: keep MFMA below
          #pragma unroll
          for (int kk = 0; kk < 16; ++kk) {
            #pragma unroll
            for (int g = 0; g < 3; ++g) {
              short8 b = *(const short8*)(WA + (size_t)(g * 16 + r16) * WA_STRIDE + kk * 32 + q * 8);
              acc[g] = __builtin_amdgcn_mfma_f32_16x16x32_bf16(af[kk], b, acc[g], 0, 0, 0);
            }
          }
        }
        #pragma unroll
        for (int j = 0; j < 4; ++j) {
          float gI = bf2f(gu[j])     + acc[0][j];
          float gO = bf2f(gu[4 + j]) + acc[1][j];
          float gG = bf2f(gu[8 + j]) + acc[2][j];
          float ig = sigm(gI), og = sigm(gO), cd = tanh_f(gG);
          float c1v = ig * cd - fj[j];
          c1[j] = c1v;
          h1w[j] = f2bf(og * tanh_f(c1v));
        }
      }
      __syncthreads();     // mid: joins wv4 slack-gate before ring overwrite
      if (wv < 4) {
        size_t hoff = ((size_t)(s & (RDEPTH - 1)) * BATCH + m0 + q * 4) * 512 + hcol;
        l2_store_4rows(h1L2 + hoff, h1w[0], h1w[1], h1w[2], h1w[3]);   // A peers (same XCD)
        llc_store_4rows(h1LLC + hoff, h1w[0], h1w[1], h1w[2], h1w[3]); // B (cross XCD)
        ushort4 hw;
        hw.x = f2bf(c1[0]); hw.y = f2bf(c1[1]); hw.z = f2bf(c1[2]); hw.w = f2bf(c1[3]);
        *(ushort4*)(HI + ((size_t)((s & (KHIST - 1)) * 16 + rg) * 16 + r16) * 4) = hw;
      }
      drain_vm();
      __syncthreads();
      if (tid == 0)
        flag_st_llc(aFlags + hs * FSTR, s + 1);
    }
  } else {
    // ---- B block ----
    unsigned short* WB = (unsigned short*)lds;                 // [64][1032]
    float* EX = (float*)(lds + 64 * WB_STRIDE * 2);            // exch [4 mi][4 g][64 lane][4]
    for (int idx = tid; idx < 64 * 128; idx += 512) {
      int rowi = idx >> 7, kc = idx & 127;
      int g = rowi >> 4, c = rowi & 15;
      const unsigned short* src = W2 + ((size_t)(g * 512 + hs * 16 + c)) * 1024 + kc * 8;
      *(short8*)(WB + rowi * WB_STRIDE + kc * 8) = *(const short8*)src;
    }
    const int mi = wv >> 1, kh = wv & 1;
    const int m0 = bs * 64 + mi * 16;
    float c2r[4] = {0.f, 0.f, 0.f, 0.f};
    int lenr[4];
    float bBr[4];
    #pragma unroll
    for (int j = 0; j < 4; ++j) lenr[j] = length[m0 + q * 4 + j];
    #pragma unroll
    for (int g = 0; g < 4; ++g) bBr[g] = bB[g * 512 + hcol];
    __syncthreads();

    for (int t = 0; t < T_STEPS; ++t) {
      // per-wave self-gated polls: kh=0 needs A done t; kh=1 needs B peers done t-1
      if (kh == 0) {
        if (lane < 32) {
          const int* f = aFlags + lane * FSTR;
          while (flag_ld_llc(f) < t + 1) __builtin_amdgcn_s_sleep(POLL_SLEEP);
        }
      } else {
        if (t > 0 && lane < 32) {
          const int* f = bFlags + lane * FSTR;
          while (flag_ld_llc(f) < t) __builtin_amdgcn_s_sleep(POLL_SLEEP);
        }
      }
      floatx4 acc[4];
      #pragma unroll
      for (int g = 0; g < 4; ++g) acc[g] = (floatx4){0.f, 0.f, 0.f, 0.f};
      bool doit = !(kh == 1 && t == 0);
      if (doit) {
        short8 af[16];
        if (kh == 0) {
          // h1 from A blocks: cross-XCD -> LLC copy
          const unsigned short* ab =
              h1LLC + ((size_t)(t & (RDEPTH - 1)) * BATCH + m0 + r16) * 512 + q * 8;
          llc_load_1k(ab, af);
        } else {
          // h2 from B peers: same XCD -> L2 path
          const unsigned short* ab =
              h2his + ((size_t)((t - 1) & (RDEPTH - 1)) * BATCH + m0 + r16) * 512 + q * 8;
          l2_load_1k(ab, af);
        }
        #pragma unroll
        for (int kk = 0; kk < 16; ++kk) {
          #pragma unroll
          for (int g = 0; g < 4; ++g) {
            short8 b = *(const short8*)(WB + (size_t)(g * 16 + r16) * WB_STRIDE + kh * 512 + kk * 32 + q * 8);
            acc[g] = __builtin_amdgcn_mfma_f32_16x16x32_bf16(af[kk], b, acc[g], 0, 0, 0);
          }
        }
      }
      if (kh == 1) {
        #pragma unroll
        for (int g = 0; g < 4; ++g)
          *(floatx4*)(EX + ((size_t)(mi * 4 + g) * 64 + lane) * 4) = acc[g];
      }
      __syncthreads();   // mid: EX handoff + peer-poll gate before h2 ring store
      if (kh == 0) {
        #pragma unroll
        for (int g = 0; g < 4; ++g)
          acc[g] += *(const floatx4*)(EX + ((size_t)(mi * 4 + g) * 64 + lane) * 4);
        unsigned short h2w[4];
        #pragma unroll
        for (int j = 0; j < 4; ++j) {
          int row = m0 + q * 4 + j;
          float gi = acc[0][j] + bBr[0];
          float gf = acc[1][j] + bBr[1];
          float gg = acc[2][j] + bBr[2];
          float go = acc[3][j] + bBr[3];
          float c2n = sigm(gf) * c2r[j] + sigm(gi) * tanh_f(gg);
          c2r[j] = c2n;
          float h2n = tanh_f(sigm(go) * tanh_f(c2n));
          h2w[j] = f2bf(h2n);
          if (lenr[j] == t) sel[(size_t)row * 512 + hcol] = h2n;
        }
        // B peers only (same XCD) -> L2 store, no LLC copy needed
        l2_store_4rows(h2his + ((size_t)(t & (RDEPTH - 1)) * BATCH + m0 + q * 4) * 512 + hcol,
                       h2w[0], h2w[1], h2w[2], h2w[3]);
      }
      drain_vm();
      __syncthreads();
      if (tid == 0)
        flag_st_llc(bFlags + hs * FSTR, t + 1);
    }
  }
}

// ---------------- output head ----------------
__global__ void out_head_kernel(const float* __restrict__ sel, const float* __restrict__ Wout,
                                const float* __restrict__ bout, float* __restrict__ out) {
  int b = blockIdx.x, lane = threadIdx.x;   // 256 blocks x 64 threads
  float acc[5] = {0.f, 0.f, 0.f, 0.f, 0.f};
  for (int j = lane; j < HDIM; j += 64) {
    float x = sel[(size_t)b * HDIM + j];
    #pragma unroll
    for (int o = 0; o < 5; ++o) acc[o] += x * Wout[o * HDIM + j];
  }
  #pragma unroll
  for (int o = 0; o < 5; ++o)
    for (int off = 32; off > 0; off >>= 1) acc[o] += __shfl_down(acc[o], off);
  if (lane == 0) {
    float v[5]; float m = -1e30f;
    #pragma unroll
    for (int o = 0; o < 5; ++o) { v[o] = acc[o] + bout[o]; m = fmaxf(m, v[o]); }
    float s = 0.f;
    #pragma unroll
    for (int o = 0; o < 5; ++o) s += __expf(v[o] - m);
    float l = logf(s) + m;
    #pragma unroll
    for (int o = 0; o < 5; ++o) out[b * 5 + o] = v[o] - l;
  }
}

// ---------------- launch ----------------
extern "C" void kernel_launch(void* const* d_in, const int* in_sizes, int n_in,
                              void* d_out, int out_size, void* d_ws, size_t ws_size,
                              hipStream_t stream) {
  const float* x      = (const float*)d_in[0];
  const int*   length = (const int*)d_in[1];
  const float* b_d    = (const float*)d_in[2];
  const float* W_mih  = (const float*)d_in[3];
  const float* W_mhh  = (const float*)d_in[4];
  const float* b_mih  = (const float*)d_in[5];
  const float* b_mhh  = (const float*)d_in[6];
  const float* W_ih   = (const float*)d_in[7];
  const float* W_hh   = (const float*)d_in[8];
  const float* b_ih   = (const float*)d_in[9];
  const float* b_hh   = (const float*)d_in[10];
  const float* W_out  = (const float*)d_in[11];
  const float* b_out  = (const float*)d_in[12];
  float* out = (float*)d_out;

  char* ws = (char*)d_ws;
  size_t off = 0;
  auto take = [&](size_t bytes) -> char* {
    char* p = ws + off;
    off += (bytes + 255) & ~(size_t)255;
    return p;
  };

  unsigned short* Xb     = (unsigned short*)take((size_t)T_STEPS * BATCH * IDIM * 2);
  unsigned short* Wmih_b = (unsigned short*)take(1536 * 512 * 2);
  unsigned short* Wmhh_b = (unsigned short*)take(1536 * 512 * 2);
  unsigned short* W2_b   = (unsigned short*)take(2048 * 1024 * 2);
  float* bA  = (float*)take(1536 * 4);
  float* bB  = (float*)take(2048 * 4);
  float* wd2 = (float*)take(KHIST * HDIM * 4);
  unsigned short* h1L2  = (unsigned short*)take((size_t)RDEPTH * BATCH * 512 * 2);
  unsigned short* h1LLC = (unsigned short*)take((size_t)RDEPTH * BATCH * 512 * 2);
  unsigned short* h2his = (unsigned short*)take((size_t)RDEPTH * BATCH * 512 * 2);
  float* sel = (float*)take((size_t)BATCH * HDIM * 4);
  int* counters = (int*)take(32768);
  unsigned short* GXh = (unsigned short*)take((size_t)T_STEPS * BATCH * 1536 * 2);
  if (off > ws_size) return;  // workspace too small -> loud validation failure

  prep_all<<<PREP_BLOCKS, 256, 0, stream>>>(x, W_mih, W_mhh, W_ih, W_hh,
                                            b_d, b_mih, b_mhh, b_ih, b_hh,
                                            Xb, Wmih_b, Wmhh_b, W2_b, wd2, bA, bB, counters);
  // 128x128 tiles: (32768/128) * (1536/128) = 256 * 12 = 3072 blocks, bn-outer
  gx_gemm_kernel<<<3072, 256, 0, stream>>>(Xb, Wmih_b, bA, GXh);

  hipFuncSetAttribute((const void*)recurrent2, hipFuncAttributeMaxDynamicSharedMemorySize, LDS_BYTES);
  void* kargs[] = { (void*)&GXh, (void*)&Wmhh_b, (void*)&W2_b, (void*)&bB, (void*)&wd2,
                    (void*)&h1L2, (void*)&h1LLC, (void*)&h2his, (void*)&sel, (void*)&length,
                    (void*)&counters };
  hipLaunchCooperativeKernel((void*)recurrent2, dim3(256), dim3(512), kargs, LDS_BYTES, stream);

  out_head_kernel<<<BATCH, 64, 0, stream>>>(sel, W_out, b_out, out);
}

// Round 12
// 1007.923 us; speedup vs baseline: 1.5240x; 1.2566x over previous
//
#include <hip/hip_runtime.h>
#include <hip/hip_cooperative_groups.h>
#include <cstdint>
#include <cstddef>

typedef __attribute__((ext_vector_type(8))) short short8;   // 8 bf16 (4 VGPRs) MFMA frag
typedef __attribute__((ext_vector_type(4))) float floatx4;  // MFMA accumulator

#define T_STEPS 128
#define BATCH   256
#define IDIM    512
#define HDIM    512
#define KHIST   32
#define RDEPTH  16

// LDS layout (recurrent2)
#define WA_STRIDE 520      // 512 + 8 pad
#define WB_STRIDE 1032     // 1024 + 8 pad
#define LDS_BYTES 148480   // B: WB 64*1032*2 + EX 16384; A: 49920 + 65536

// flags: one per 128B LLC line (FSTR ints apart)
#define FSTR 32
#define POLL_SLEEP 8

// Exchange buffers use a BLOCK-CHUNKED layout (r11 change):
//   buf[slot16][chain4][hs32][row64][col16]  (shorts)
// chunk base (shorts) = ((slot*4+chain)*32 + hs)*1024; block hs owns a
// contiguous 2KB chunk per slot -> producer stores fill whole 128B lines
// (one line per 16-lane group), single-owner lines, no cross-block
// partial-line merge. Consumers read identical bytes via the bijection:
//   row-major (row, col) -> chunk hs'=col>>4, offset row*16 + (col&15).

__device__ __forceinline__ unsigned short f2bf(float x) {
  union { float f; unsigned u; } v; v.f = x;
  unsigned r = v.u + 0x7fffu + ((v.u >> 16) & 1u);   // RNE
  return (unsigned short)(r >> 16);
}
__device__ __forceinline__ float bf2f(unsigned short s) {
  union { unsigned u; float f; } v; v.u = ((unsigned)s) << 16; return v.f;
}
__device__ __forceinline__ float sigm(float x) { return 1.0f / (1.0f + __expf(-x)); }
__device__ __forceinline__ float tanh_f(float x) {
  float ax = fabsf(x);
  float e = __expf(-2.0f * ax);
  float t = (1.0f - e) / (1.0f + e);
  return x < 0.0f ? -t : t;
}

// ---- coherent exchange primitives ----
// sc0 sc1 : LLC scope (r6-proven) — cross-XCD edges + ALL flags.
// sc0     : L2 scope — same-XCD producer->consumer (validated r10: correctness
//           held with L2-routed same-XCD exchange). Flags never sc0-only.
__device__ __forceinline__ void llc_issue_16B(const unsigned short* p, short8* r) {
  asm volatile("global_load_dwordx4 %0, %1, off sc0 sc1"
               : "=v"(*r) : "v"(p) : "memory");
}
__device__ __forceinline__ void l2_issue_16B(const unsigned short* p, short8* r) {
  asm volatile("global_load_dwordx4 %0, %1, off sc0"
               : "=v"(*r) : "v"(p) : "memory");
}
// 4 rows of the block-owned chunk: stride 16 shorts = 32B -> one full 128B
// line per 16-lane group.
__device__ __forceinline__ void llc_store_4rows32(unsigned short* p,
                                                  unsigned short a, unsigned short b,
                                                  unsigned short c, unsigned short d) {
  asm volatile(
    "global_store_short %4, %0, off sc0 sc1\n\t"
    "global_store_short %4, %1, off offset:32 sc0 sc1\n\t"
    "global_store_short %4, %2, off offset:64 sc0 sc1\n\t"
    "global_store_short %4, %3, off offset:96 sc0 sc1"
    :: "v"((unsigned)a), "v"((unsigned)b), "v"((unsigned)c), "v"((unsigned)d), "v"(p)
    : "memory");
}
__device__ __forceinline__ void l2_store_4rows32(unsigned short* p,
                                                 unsigned short a, unsigned short b,
                                                 unsigned short c, unsigned short d) {
  asm volatile(
    "global_store_short %4, %0, off sc0\n\t"
    "global_store_short %4, %1, off offset:32 sc0\n\t"
    "global_store_short %4, %2, off offset:64 sc0\n\t"
    "global_store_short %4, %3, off offset:96 sc0"
    :: "v"((unsigned)a), "v"((unsigned)b), "v"((unsigned)c), "v"((unsigned)d), "v"(p)
    : "memory");
}
__device__ __forceinline__ int flag_ld_llc(const int* p) {
  int v; asm volatile("global_load_dword %0, %1, off sc0 sc1\n\ts_waitcnt vmcnt(0)"
                      : "=v"(v) : "v"(p) : "memory"); return v;
}
__device__ __forceinline__ void flag_st_llc(int* p, int v) {
  asm volatile("global_store_dword %0, %1, off sc0 sc1" :: "v"(p), "v"(v) : "memory");
}
__device__ __forceinline__ void drain_vm() {
  asm volatile("s_waitcnt vmcnt(0)" ::: "memory");
}

// ---------------- single fused prep kernel ----------------
// counters: aFlags at bs*1024 + hs*FSTR; bFlags at 4096 + bs*1024 + hs*FSTR.
// 8192 ints total -> zero with 32 blocks x 256.
#define PREP_BLOCKS 20016
__global__ __launch_bounds__(256) void prep_all(
    const float* __restrict__ x, const float* __restrict__ Wmih, const float* __restrict__ Wmhh,
    const float* __restrict__ Wih, const float* __restrict__ Whh,
    const float* __restrict__ b_d, const float* __restrict__ b_mih, const float* __restrict__ b_mhh,
    const float* __restrict__ b_ih, const float* __restrict__ b_hh,
    unsigned short* __restrict__ Xb, unsigned short* __restrict__ Wmih_b,
    unsigned short* __restrict__ Wmhh_b, unsigned short* __restrict__ W2,
    float* __restrict__ wd2, float* __restrict__ bA, float* __restrict__ bB,
    int* __restrict__ counters) {
  const int blk = blockIdx.x, tid = threadIdx.x;
  if (blk < 16384) {
    int i = blk * 256 + tid;
    float4 v = reinterpret_cast<const float4*>(x)[i];
    ushort4 o; o.x = f2bf(v.x); o.y = f2bf(v.y); o.z = f2bf(v.z); o.w = f2bf(v.w);
    reinterpret_cast<ushort4*>(Xb)[i] = o;
  } else if (blk < 17152) {
    int i = (blk - 16384) * 256 + tid;
    float4 v = reinterpret_cast<const float4*>(Wmih)[i];
    ushort4 o; o.x = f2bf(v.x); o.y = f2bf(v.y); o.z = f2bf(v.z); o.w = f2bf(v.w);
    reinterpret_cast<ushort4*>(Wmih_b)[i] = o;
  } else if (blk < 17920) {
    int i = (blk - 17152) * 256 + tid;
    float4 v = reinterpret_cast<const float4*>(Wmhh)[i];
    ushort4 o; o.x = f2bf(v.x); o.y = f2bf(v.y); o.z = f2bf(v.z); o.w = f2bf(v.w);
    reinterpret_cast<ushort4*>(Wmhh_b)[i] = o;
  } else if (blk < 19968) {
    int i4 = (blk - 17920) * 256 + tid;
    int i = i4 * 4; int n = i >> 10; int k = i & 1023;
    float4 v = (k < 512) ? reinterpret_cast<const float4*>(Wih + n * 512 + k)[0]
                         : reinterpret_cast<const float4*>(Whh + n * 512 + (k - 512))[0];
    ushort4 o; o.x = f2bf(v.x); o.y = f2bf(v.y); o.z = f2bf(v.z); o.w = f2bf(v.w);
    reinterpret_cast<ushort4*>(W2 + i)[0] = o;
  } else if (blk < 19984) {
    int t = (blk - 19968) * 256 + tid;
    if (t < 512) {
      float d = 0.5f * sigm(b_d[t]);
      float c = 1.0f;
      for (int i = 0; i < KHIST; ++i) {
        c *= ((float)i - d) / ((float)i + 1.0f);
        wd2[i * HDIM + t] = c;
      }
    } else if (t < 2048) {
      int n = t - 512;
      bA[n] = b_mih[n] + b_mhh[n];
    } else {
      int n = t - 2048;
      bB[n] = b_ih[n] + b_hh[n];
    }
  } else {
    int i = (blk - 19984) * 256 + tid;
    counters[i] = 0;
  }
}

// ---------------- input-projection GEMM: 128x128 tile, BK=32, dbuf LDS ----------------
__global__ __launch_bounds__(256) void gx_gemm_kernel(const unsigned short* __restrict__ Xb,
                                                      const unsigned short* __restrict__ Wb,
                                                      const float* __restrict__ bA,
                                                      unsigned short* __restrict__ GXh) {
  __shared__ unsigned short As[2][128 * 32];
  __shared__ unsigned short Bs[2][128 * 32];
  const int tid = threadIdx.x;
  const int lane = tid & 63;
  const int wv = tid >> 6;
  const int q = lane >> 4, r16 = lane & 15;
  const int wr = wv >> 1, wc = wv & 1;
  const int bid = (int)blockIdx.x;
  const int m0 = (bid & 255) * 128;
  const int n0 = (bid >> 8) * 128;

  const int sr0 = tid >> 2, sc0 = (tid & 3) * 8;
  const int sr1 = (256 + tid) >> 2, sc1 = (tid & 3) * 8;

  floatx4 acc[4][4];
  #pragma unroll
  for (int i = 0; i < 4; ++i)
    #pragma unroll
    for (int j = 0; j < 4; ++j) acc[i][j] = (floatx4){0.f, 0.f, 0.f, 0.f};

  {
    short8 a0 = *(const short8*)(Xb + (size_t)(m0 + sr0) * IDIM + sc0);
    short8 a1 = *(const short8*)(Xb + (size_t)(m0 + sr1) * IDIM + sc1);
    short8 b0 = *(const short8*)(Wb + (size_t)(n0 + sr0) * IDIM + sc0);
    short8 b1 = *(const short8*)(Wb + (size_t)(n0 + sr1) * IDIM + sc1);
    *(short8*)(As[0] + sr0 * 32 + sc0) = a0;
    *(short8*)(As[0] + sr1 * 32 + sc1) = a1;
    *(short8*)(Bs[0] + sr0 * 32 + sc0) = b0;
    *(short8*)(Bs[0] + sr1 * 32 + sc1) = b1;
  }

  for (int t = 0; t < 16; ++t) {
    const int cur = t & 1;
    __syncthreads();
    short8 a0, a1, b0, b1;
    if (t < 15) {
      int k0 = (t + 1) * 32;
      a0 = *(const short8*)(Xb + (size_t)(m0 + sr0) * IDIM + k0 + sc0);
      a1 = *(const short8*)(Xb + (size_t)(m0 + sr1) * IDIM + k0 + sc1);
      b0 = *(const short8*)(Wb + (size_t)(n0 + sr0) * IDIM + k0 + sc0);
      b1 = *(const short8*)(Wb + (size_t)(n0 + sr1) * IDIM + k0 + sc1);
    }
    short8 af[4], bf[4];
    #pragma unroll
    for (int i = 0; i < 4; ++i)
      af[i] = *(const short8*)(As[cur] + (wr * 64 + i * 16 + r16) * 32 + q * 8);
    #pragma unroll
    for (int j = 0; j < 4; ++j)
      bf[j] = *(const short8*)(Bs[cur] + (wc * 64 + j * 16 + r16) * 32 + q * 8);
    #pragma unroll
    for (int i = 0; i < 4; ++i)
      #pragma unroll
      for (int j = 0; j < 4; ++j)
        acc[i][j] = __builtin_amdgcn_mfma_f32_16x16x32_bf16(af[i], bf[j], acc[i][j], 0, 0, 0);
    if (t < 15) {
      *(short8*)(As[cur ^ 1] + sr0 * 32 + sc0) = a0;
      *(short8*)(As[cur ^ 1] + sr1 * 32 + sc1) = a1;
      *(short8*)(Bs[cur ^ 1] + sr0 * 32 + sc0) = b0;
      *(short8*)(Bs[cur ^ 1] + sr1 * 32 + sc1) = b1;
    }
  }

  #pragma unroll
  for (int j = 0; j < 4; ++j) {
    int col = n0 + wc * 64 + j * 16 + r16;
    float bias = bA[col];
    #pragma unroll
    for (int i = 0; i < 4; ++i) {
      #pragma unroll
      for (int jj = 0; jj < 4; ++jj) {
        int row = m0 + wr * 64 + i * 16 + q * 4 + jj;
        GXh[(size_t)row * 1536 + col] = f2bf(acc[i][j][jj] + bias);
      }
    }
  }
}

// ---------------- async persistent recurrent kernel ----------------
// r11 change vs r10: block-chunked exchange layout (see top comment) so
// producer stores are full-line single-owner writes; consumer loads permuted
// per-kk (chunk stride 2048 shorts). Protocol, scopes, and everything else
// identical to r10 (passing, recurrent2 ~1073us).
__global__ __launch_bounds__(512, 1) void recurrent2(
    const unsigned short* __restrict__ GXh,    // (T*256 x 1536) bf16
    const unsigned short* __restrict__ Wmhh,   // (1536 x 512) bf16 N-major
    const unsigned short* __restrict__ W2,     // (2048 x 1024) bf16 N-major
    const float* __restrict__ bB,              // (2048)
    const float* __restrict__ wd2,             // (32 x 512)
    unsigned short* __restrict__ h1L2,         // chunked, A-XCD L2 copy
    unsigned short* __restrict__ h1LLC,        // chunked, LLC copy for B
    unsigned short* __restrict__ h2his,        // chunked, B-XCD L2
    float* __restrict__ sel,                   // (256 x 512) fp32
    const int* __restrict__ length,
    int* __restrict__ counters) {
  extern __shared__ char lds[];
  const int tid = threadIdx.x;
  const int lane = tid & 63;
  const int wv = tid >> 6;                 // 0..7
  const int q = lane >> 4, r16 = lane & 15;
  const int xcd = (int)blockIdx.x & 7;
  const int bs = xcd >> 1;
  const bool isA = (xcd & 1) == 0;
  const int hs = (int)blockIdx.x >> 3;
  const int hcol = hs * 16 + r16;
  int* aFlags = counters + bs * 1024;
  int* bFlags = counters + 4096 + bs * 1024;

  if (isA) {
    unsigned short* WA = (unsigned short*)lds;                        // [48][520]
    unsigned short* HI = (unsigned short*)(lds + 48 * WA_STRIDE * 2); // 64KB hist
    for (int idx = tid; idx < 48 * 64; idx += 512) {
      int rowi = idx >> 6, kc = idx & 63;
      int g = rowi >> 4, c = rowi & 15;
      const unsigned short* src = Wmhh + ((size_t)(g * 512 + hs * 16 + c)) * 512 + kc * 8;
      *(short8*)(WA + rowi * WA_STRIDE + kc * 8) = *(const short8*)src;
    }
    for (int idx = tid; idx < 4096; idx += 512)
      ((uint4*)HI)[idx] = (uint4){0, 0, 0, 0};
    float wdr[KHIST];
    #pragma unroll
    for (int l = 0; l < KHIST; ++l) wdr[l] = wd2[l * HDIM + hcol];
    __syncthreads();

    const int mi = wv & 3;
    const int m0 = bs * 64 + mi * 16;
    const int rg = mi * 4 + q;

    for (int s = 0; s < T_STEPS; ++s) {
      // GX prefetch (bf16 cached loads; complete during the poll)
      unsigned short gu[12];
      if (wv < 4) {
        #pragma unroll
        for (int j = 0; j < 4; ++j) {
          int row = m0 + q * 4 + j;
          size_t gidx = ((size_t)s * BATCH + row) * 1536 + hcol;
          gu[j]     = GXh[gidx];
          gu[4 + j] = GXh[gidx + 512];
          gu[8 + j] = GXh[gidx + 1024];
        }
      }
      // per-wave self-gated polls (no barrier between detect and data issue)
      if (wv < 4) {
        if (s > 0 && lane < 32) {
          const int* f = aFlags + lane * FSTR;
          while (flag_ld_llc(f) < s) __builtin_amdgcn_s_sleep(POLL_SLEEP);
        }
      } else if (wv == 4) {
        int tgt = s - (RDEPTH - 1);        // B slack gate (ring overwrite safety)
        if (tgt > 0 && lane < 32) {
          const int* f = bFlags + lane * FSTR;
          while (flag_ld_llc(f) < tgt) __builtin_amdgcn_s_sleep(POLL_SLEEP);
        }
      }
      float c1[4];
      unsigned short h1w[4];
      if (wv < 4) {
        short8 af[16];
        if (s > 0) {
          // issue h1 tile load from chunked layout (same-XCD L2 copy)
          const unsigned short* ab = h1L2 +
              (((size_t)((s - 1) & 15) * 4 + bs) << 15) +
              (size_t)(mi * 16 + r16) * 16 + (q & 1) * 8 + (q >> 1) * 1024;
          #pragma unroll
          for (int kk = 0; kk < 16; ++kk)
            l2_issue_16B(ab + (size_t)kk * 2048, &af[kk]);
        }
        // frac-diff filter (wave-private LDS rows) overlaps the load flight
        float f0 = 0.f, f1 = 0.f, f2 = 0.f, f3 = 0.f;
        #pragma unroll
        for (int jj = 1; jj <= KHIST; ++jj) {
          int sl = (s - jj) & (KHIST - 1);
          ushort4 hv = *(const ushort4*)(HI + ((size_t)(sl * 16 + rg) * 16 + r16) * 4);
          float wc = wdr[jj - 1];
          f0 += wc * bf2f(hv.x); f1 += wc * bf2f(hv.y);
          f2 += wc * bf2f(hv.z); f3 += wc * bf2f(hv.w);
        }
        float fj[4] = {f0, f1, f2, f3};
        floatx4 acc[3];
        #pragma unroll
        for (int g = 0; g < 3; ++g) acc[g] = (floatx4){0.f, 0.f, 0.f, 0.f};
        if (s > 0) {
          drain_vm();                               // af now valid
          __builtin_amdgcn_sched_barrier(0);        // rule #18: keep MFMA below
          #pragma unroll
          for (int kk = 0; kk < 16; ++kk) {
            #pragma unroll
            for (int g = 0; g < 3; ++g) {
              short8 b = *(const short8*)(WA + (size_t)(g * 16 + r16) * WA_STRIDE + kk * 32 + q * 8);
              acc[g] = __builtin_amdgcn_mfma_f32_16x16x32_bf16(af[kk], b, acc[g], 0, 0, 0);
            }
          }
        }
        #pragma unroll
        for (int j = 0; j < 4; ++j) {
          float gI = bf2f(gu[j])     + acc[0][j];
          float gO = bf2f(gu[4 + j]) + acc[1][j];
          float gG = bf2f(gu[8 + j]) + acc[2][j];
          float ig = sigm(gI), og = sigm(gO), cd = tanh_f(gG);
          float c1v = ig * cd - fj[j];
          c1[j] = c1v;
          h1w[j] = f2bf(og * tanh_f(c1v));
        }
      }
      __syncthreads();     // mid: joins wv4 slack-gate before ring overwrite
      if (wv < 4) {
        // block-owned chunk: 4 rows at 32B stride -> full 128B line per q-group
        size_t hoff = (((size_t)(s & 15) * 4 + bs) << 15) + (size_t)hs * 1024 +
                      (size_t)(mi * 16 + q * 4) * 16 + r16;
        l2_store_4rows32(h1L2 + hoff, h1w[0], h1w[1], h1w[2], h1w[3]);   // A peers
        llc_store_4rows32(h1LLC + hoff, h1w[0], h1w[1], h1w[2], h1w[3]); // B (cross XCD)
        ushort4 hw;
        hw.x = f2bf(c1[0]); hw.y = f2bf(c1[1]); hw.z = f2bf(c1[2]); hw.w = f2bf(c1[3]);
        *(ushort4*)(HI + ((size_t)((s & (KHIST - 1)) * 16 + rg) * 16 + r16) * 4) = hw;
      }
      drain_vm();
      __syncthreads();
      if (tid == 0)
        flag_st_llc(aFlags + hs * FSTR, s + 1);
    }
  } else {
    // ---- B block ----
    unsigned short* WB = (unsigned short*)lds;                 // [64][1032]
    float* EX = (float*)(lds + 64 * WB_STRIDE * 2);            // exch [4 mi][4 g][64 lane][4]
    for (int idx = tid; idx < 64 * 128; idx += 512) {
      int rowi = idx >> 7, kc = idx & 127;
      int g = rowi >> 4, c = rowi & 15;
      const unsigned short* src = W2 + ((size_t)(g * 512 + hs * 16 + c)) * 1024 + kc * 8;
      *(short8*)(WB + rowi * WB_STRIDE + kc * 8) = *(const short8*)src;
    }
    const int mi = wv >> 1, kh = wv & 1;
    const int m0 = bs * 64 + mi * 16;
    float c2r[4] = {0.f, 0.f, 0.f, 0.f};
    int lenr[4];
    float bBr[4];
    #pragma unroll
    for (int j = 0; j < 4; ++j) lenr[j] = length[m0 + q * 4 + j];
    #pragma unroll
    for (int g = 0; g < 4; ++g) bBr[g] = bB[g * 512 + hcol];
    __syncthreads();

    for (int t = 0; t < T_STEPS; ++t) {
      // per-wave self-gated polls: kh=0 needs A done t; kh=1 needs B peers done t-1
      if (kh == 0) {
        if (lane < 32) {
          const int* f = aFlags + lane * FSTR;
          while (flag_ld_llc(f) < t + 1) __builtin_amdgcn_s_sleep(POLL_SLEEP);
        }
      } else {
        if (t > 0 && lane < 32) {
          const int* f = bFlags + lane * FSTR;
          while (flag_ld_llc(f) < t) __builtin_amdgcn_s_sleep(POLL_SLEEP);
        }
      }
      floatx4 acc[4];
      #pragma unroll
      for (int g = 0; g < 4; ++g) acc[g] = (floatx4){0.f, 0.f, 0.f, 0.f};
      bool doit = !(kh == 1 && t == 0);
      if (doit) {
        short8 af[16];
        const size_t lrow = (size_t)(mi * 16 + r16) * 16 + (q & 1) * 8 + (q >> 1) * 1024;
        if (kh == 0) {
          // h1 from A blocks: cross-XCD -> LLC copy, chunked layout
          const unsigned short* ab = h1LLC + (((size_t)(t & 15) * 4 + bs) << 15) + lrow;
          #pragma unroll
          for (int kk = 0; kk < 16; ++kk)
            llc_issue_16B(ab + (size_t)kk * 2048, &af[kk]);
        } else {
          // h2 from B peers: same XCD -> L2 path, chunked layout
          const unsigned short* ab = h2his + (((size_t)((t - 1) & 15) * 4 + bs) << 15) + lrow;
          #pragma unroll
          for (int kk = 0; kk < 16; ++kk)
            l2_issue_16B(ab + (size_t)kk * 2048, &af[kk]);
        }
        drain_vm();
        __builtin_amdgcn_sched_barrier(0);          // rule #18
        #pragma unroll
        for (int kk = 0; kk < 16; ++kk) {
          #pragma unroll
          for (int g = 0; g < 4; ++g) {
            short8 b = *(const short8*)(WB + (size_t)(g * 16 + r16) * WB_STRIDE + kh * 512 + kk * 32 + q * 8);
            acc[g] = __builtin_amdgcn_mfma_f32_16x16x32_bf16(af[kk], b, acc[g], 0, 0, 0);
          }
        }
      }
      if (kh == 1) {
        #pragma unroll
        for (int g = 0; g < 4; ++g)
          *(floatx4*)(EX + ((size_t)(mi * 4 + g) * 64 + lane) * 4) = acc[g];
      }
      __syncthreads();   // mid: EX handoff + peer-poll gate before h2 ring store
      if (kh == 0) {
        #pragma unroll
        for (int g = 0; g < 4; ++g)
          acc[g] += *(const floatx4*)(EX + ((size_t)(mi * 4 + g) * 64 + lane) * 4);
        unsigned short h2w[4];
        #pragma unroll
        for (int j = 0; j < 4; ++j) {
          int row = m0 + q * 4 + j;
          float gi = acc[0][j] + bBr[0];
          float gf = acc[1][j] + bBr[1];
          float gg = acc[2][j] + bBr[2];
          float go = acc[3][j] + bBr[3];
          float c2n = sigm(gf) * c2r[j] + sigm(gi) * tanh_f(gg);
          c2r[j] = c2n;
          float h2n = tanh_f(sigm(go) * tanh_f(c2n));
          h2w[j] = f2bf(h2n);
          if (lenr[j] == t) sel[(size_t)row * 512 + hcol] = h2n;
        }
        // B peers only (same XCD) -> L2 store, chunked full-line pattern
        size_t hoff = (((size_t)(t & 15) * 4 + bs) << 15) + (size_t)hs * 1024 +
                      (size_t)(mi * 16 + q * 4) * 16 + r16;
        l2_store_4rows32(h2his + hoff, h2w[0], h2w[1], h2w[2], h2w[3]);
      }
      drain_vm();
      __syncthreads();
      if (tid == 0)
        flag_st_llc(bFlags + hs * FSTR, t + 1);
    }
  }
}

// ---------------- output head ----------------
__global__ void out_head_kernel(const float* __restrict__ sel, const float* __restrict__ Wout,
                                const float* __restrict__ bout, float* __restrict__ out) {
  int b = blockIdx.x, lane = threadIdx.x;   // 256 blocks x 64 threads
  float acc[5] = {0.f, 0.f, 0.f, 0.f, 0.f};
  for (int j = lane; j < HDIM; j += 64) {
    float x = sel[(size_t)b * HDIM + j];
    #pragma unroll
    for (int o = 0; o < 5; ++o) acc[o] += x * Wout[o * HDIM + j];
  }
  #pragma unroll
  for (int o = 0; o < 5; ++o)
    for (int off = 32; off > 0; off >>= 1) acc[o] += __shfl_down(acc[o], off);
  if (lane == 0) {
    float v[5]; float m = -1e30f;
    #pragma unroll
    for (int o = 0; o < 5; ++o) { v[o] = acc[o] + bout[o]; m = fmaxf(m, v[o]); }
    float s = 0.f;
    #pragma unroll
    for (int o = 0; o < 5; ++o) s += __expf(v[o] - m);
    float l = logf(s) + m;
    #pragma unroll
    for (int o = 0; o < 5; ++o) out[b * 5 + o] = v[o] - l;
  }
}

// ---------------- launch ----------------
extern "C" void kernel_launch(void* const* d_in, const int* in_sizes, int n_in,
                              void* d_out, int out_size, void* d_ws, size_t ws_size,
                              hipStream_t stream) {
  const float* x      = (const float*)d_in[0];
  const int*   length = (const int*)d_in[1];
  const float* b_d    = (const float*)d_in[2];
  const float* W_mih  = (const float*)d_in[3];
  const float* W_mhh  = (const float*)d_in[4];
  const float* b_mih  = (const float*)d_in[5];
  const float* b_mhh  = (const float*)d_in[6];
  const float* W_ih   = (const float*)d_in[7];
  const float* W_hh   = (const float*)d_in[8];
  const float* b_ih   = (const float*)d_in[9];
  const float* b_hh   = (const float*)d_in[10];
  const float* W_out  = (const float*)d_in[11];
  const float* b_out  = (const float*)d_in[12];
  float* out = (float*)d_out;

  char* ws = (char*)d_ws;
  size_t off = 0;
  auto take = [&](size_t bytes) -> char* {
    char* p = ws + off;
    off += (bytes + 255) & ~(size_t)255;
    return p;
  };

  unsigned short* Xb     = (unsigned short*)take((size_t)T_STEPS * BATCH * IDIM * 2);
  unsigned short* Wmih_b = (unsigned short*)take(1536 * 512 * 2);
  unsigned short* Wmhh_b = (unsigned short*)take(1536 * 512 * 2);
  unsigned short* W2_b   = (unsigned short*)take(2048 * 1024 * 2);
  float* bA  = (float*)take(1536 * 4);
  float* bB  = (float*)take(2048 * 4);
  float* wd2 = (float*)take(KHIST * HDIM * 4);
  unsigned short* h1L2  = (unsigned short*)take((size_t)RDEPTH * BATCH * 512 * 2);
  unsigned short* h1LLC = (unsigned short*)take((size_t)RDEPTH * BATCH * 512 * 2);
  unsigned short* h2his = (unsigned short*)take((size_t)RDEPTH * BATCH * 512 * 2);
  float* sel = (float*)take((size_t)BATCH * HDIM * 4);
  int* counters = (int*)take(32768);
  unsigned short* GXh = (unsigned short*)take((size_t)T_STEPS * BATCH * 1536 * 2);
  if (off > ws_size) return;  // workspace too small -> loud validation failure

  prep_all<<<PREP_BLOCKS, 256, 0, stream>>>(x, W_mih, W_mhh, W_ih, W_hh,
                                            b_d, b_mih, b_mhh, b_ih, b_hh,
                                            Xb, Wmih_b, Wmhh_b, W2_b, wd2, bA, bB, counters);
  // 128x128 tiles: (32768/128) * (1536/128) = 256 * 12 = 3072 blocks, bn-outer
  gx_gemm_kernel<<<3072, 256, 0, stream>>>(Xb, Wmih_b, bA, GXh);

  hipFuncSetAttribute((const void*)recurrent2, hipFuncAttributeMaxDynamicSharedMemorySize, LDS_BYTES);
  void* kargs[] = { (void*)&GXh, (void*)&Wmhh_b, (void*)&W2_b, (void*)&bB, (void*)&wd2,
                    (void*)&h1L2, (void*)&h1LLC, (void*)&h2his, (void*)&sel, (void*)&length,
                    (void*)&counters };
  hipLaunchCooperativeKernel((void*)recurrent2, dim3(256), dim3(512), kargs, LDS_BYTES, stream);

  out_head_kernel<<<BATCH, 64, 0, stream>>>(sel, W_out, b_out, out);
}

// Round 13
// 970.246 us; speedup vs baseline: 1.5832x; 1.0388x over previous
//
#include <hip/hip_runtime.h>
#include <hip/hip_cooperative_groups.h>
#include <cstdint>
#include <cstddef>

typedef __attribute__((ext_vector_type(8))) short short8;   // 8 bf16 (4 VGPRs) MFMA frag
typedef __attribute__((ext_vector_type(4))) float floatx4;  // MFMA accumulator

#define T_STEPS 128
#define BATCH   256
#define IDIM    512
#define HDIM    512
#define KHIST   32
#define RDEPTH  16

// LDS layout (recurrent2)
#define WA_STRIDE 520      // 512 + 8 pad
#define WB_STRIDE 1032     // 1024 + 8 pad
#define LDS_BYTES 148480   // B: WB 64*1032*2 + EX 16384; A: 49920 + 65536

// flags: one per 128B LLC line (FSTR ints apart)
#define FSTR 32
#define POLL_SLEEP 8

// Exchange buffers: BLOCK-CHUNKED layout (r12-proven win):
//   buf[slot16][chain4][hs32][row64][col16] (shorts); block hs owns a
//   contiguous 2KB chunk per slot -> full-line single-owner stores.
// r13 changes:
//  * A defers its h1LLC stores to the NEXT step's poll slack (critical drain
//    covers only L2 stores); B gates h1 reads at aFlags >= t+2; post-loop
//    publish T_STEPS+1 covers the tail. Mid-barrier in A removed (it only
//    ordered the slack gate vs the LLC ring overwrite, now deferred).
//  * B role swap: epilogue wave (kh=0) consumes h2[t-1] + h2-part MFMA;
//    kh=1 computes h1-part early and deposits EX before the barrier.

__device__ __forceinline__ unsigned short f2bf(float x) {
  union { float f; unsigned u; } v; v.f = x;
  unsigned r = v.u + 0x7fffu + ((v.u >> 16) & 1u);   // RNE
  return (unsigned short)(r >> 16);
}
__device__ __forceinline__ float bf2f(unsigned short s) {
  union { unsigned u; float f; } v; v.u = ((unsigned)s) << 16; return v.f;
}
__device__ __forceinline__ float sigm(float x) { return 1.0f / (1.0f + __expf(-x)); }
__device__ __forceinline__ float tanh_f(float x) {
  float ax = fabsf(x);
  float e = __expf(-2.0f * ax);
  float t = (1.0f - e) / (1.0f + e);
  return x < 0.0f ? -t : t;
}

// ---- coherent exchange primitives ----
__device__ __forceinline__ void llc_issue_16B(const unsigned short* p, short8* r) {
  asm volatile("global_load_dwordx4 %0, %1, off sc0 sc1"
               : "=v"(*r) : "v"(p) : "memory");
}
__device__ __forceinline__ void l2_issue_16B(const unsigned short* p, short8* r) {
  asm volatile("global_load_dwordx4 %0, %1, off sc0"
               : "=v"(*r) : "v"(p) : "memory");
}
__device__ __forceinline__ void llc_store_4rows32(unsigned short* p,
                                                  unsigned short a, unsigned short b,
                                                  unsigned short c, unsigned short d) {
  asm volatile(
    "global_store_short %4, %0, off sc0 sc1\n\t"
    "global_store_short %4, %1, off offset:32 sc0 sc1\n\t"
    "global_store_short %4, %2, off offset:64 sc0 sc1\n\t"
    "global_store_short %4, %3, off offset:96 sc0 sc1"
    :: "v"((unsigned)a), "v"((unsigned)b), "v"((unsigned)c), "v"((unsigned)d), "v"(p)
    : "memory");
}
__device__ __forceinline__ void l2_store_4rows32(unsigned short* p,
                                                 unsigned short a, unsigned short b,
                                                 unsigned short c, unsigned short d) {
  asm volatile(
    "global_store_short %4, %0, off sc0\n\t"
    "global_store_short %4, %1, off offset:32 sc0\n\t"
    "global_store_short %4, %2, off offset:64 sc0\n\t"
    "global_store_short %4, %3, off offset:96 sc0"
    :: "v"((unsigned)a), "v"((unsigned)b), "v"((unsigned)c), "v"((unsigned)d), "v"(p)
    : "memory");
}
__device__ __forceinline__ int flag_ld_llc(const int* p) {
  int v; asm volatile("global_load_dword %0, %1, off sc0 sc1\n\ts_waitcnt vmcnt(0)"
                      : "=v"(v) : "v"(p) : "memory"); return v;
}
__device__ __forceinline__ void flag_st_llc(int* p, int v) {
  asm volatile("global_store_dword %0, %1, off sc0 sc1" :: "v"(p), "v"(v) : "memory");
}
__device__ __forceinline__ void drain_vm() {
  asm volatile("s_waitcnt vmcnt(0)" ::: "memory");
}

// ---------------- single fused prep kernel ----------------
#define PREP_BLOCKS 20016
__global__ __launch_bounds__(256) void prep_all(
    const float* __restrict__ x, const float* __restrict__ Wmih, const float* __restrict__ Wmhh,
    const float* __restrict__ Wih, const float* __restrict__ Whh,
    const float* __restrict__ b_d, const float* __restrict__ b_mih, const float* __restrict__ b_mhh,
    const float* __restrict__ b_ih, const float* __restrict__ b_hh,
    unsigned short* __restrict__ Xb, unsigned short* __restrict__ Wmih_b,
    unsigned short* __restrict__ Wmhh_b, unsigned short* __restrict__ W2,
    float* __restrict__ wd2, float* __restrict__ bA, float* __restrict__ bB,
    int* __restrict__ counters) {
  const int blk = blockIdx.x, tid = threadIdx.x;
  if (blk < 16384) {
    int i = blk * 256 + tid;
    float4 v = reinterpret_cast<const float4*>(x)[i];
    ushort4 o; o.x = f2bf(v.x); o.y = f2bf(v.y); o.z = f2bf(v.z); o.w = f2bf(v.w);
    reinterpret_cast<ushort4*>(Xb)[i] = o;
  } else if (blk < 17152) {
    int i = (blk - 16384) * 256 + tid;
    float4 v = reinterpret_cast<const float4*>(Wmih)[i];
    ushort4 o; o.x = f2bf(v.x); o.y = f2bf(v.y); o.z = f2bf(v.z); o.w = f2bf(v.w);
    reinterpret_cast<ushort4*>(Wmih_b)[i] = o;
  } else if (blk < 17920) {
    int i = (blk - 17152) * 256 + tid;
    float4 v = reinterpret_cast<const float4*>(Wmhh)[i];
    ushort4 o; o.x = f2bf(v.x); o.y = f2bf(v.y); o.z = f2bf(v.z); o.w = f2bf(v.w);
    reinterpret_cast<ushort4*>(Wmhh_b)[i] = o;
  } else if (blk < 19968) {
    int i4 = (blk - 17920) * 256 + tid;
    int i = i4 * 4; int n = i >> 10; int k = i & 1023;
    float4 v = (k < 512) ? reinterpret_cast<const float4*>(Wih + n * 512 + k)[0]
                         : reinterpret_cast<const float4*>(Whh + n * 512 + (k - 512))[0];
    ushort4 o; o.x = f2bf(v.x); o.y = f2bf(v.y); o.z = f2bf(v.z); o.w = f2bf(v.w);
    reinterpret_cast<ushort4*>(W2 + i)[0] = o;
  } else if (blk < 19984) {
    int t = (blk - 19968) * 256 + tid;
    if (t < 512) {
      float d = 0.5f * sigm(b_d[t]);
      float c = 1.0f;
      for (int i = 0; i < KHIST; ++i) {
        c *= ((float)i - d) / ((float)i + 1.0f);
        wd2[i * HDIM + t] = c;
      }
    } else if (t < 2048) {
      int n = t - 512;
      bA[n] = b_mih[n] + b_mhh[n];
    } else {
      int n = t - 2048;
      bB[n] = b_ih[n] + b_hh[n];
    }
  } else {
    int i = (blk - 19984) * 256 + tid;
    counters[i] = 0;
  }
}

// ---------------- input-projection GEMM: 128x128 tile, BK=32, dbuf LDS ----------------
__global__ __launch_bounds__(256) void gx_gemm_kernel(const unsigned short* __restrict__ Xb,
                                                      const unsigned short* __restrict__ Wb,
                                                      const float* __restrict__ bA,
                                                      unsigned short* __restrict__ GXh) {
  __shared__ unsigned short As[2][128 * 32];
  __shared__ unsigned short Bs[2][128 * 32];
  const int tid = threadIdx.x;
  const int lane = tid & 63;
  const int wv = tid >> 6;
  const int q = lane >> 4, r16 = lane & 15;
  const int wr = wv >> 1, wc = wv & 1;
  const int bid = (int)blockIdx.x;
  const int m0 = (bid & 255) * 128;
  const int n0 = (bid >> 8) * 128;

  const int sr0 = tid >> 2, sc0 = (tid & 3) * 8;
  const int sr1 = (256 + tid) >> 2, sc1 = (tid & 3) * 8;

  floatx4 acc[4][4];
  #pragma unroll
  for (int i = 0; i < 4; ++i)
    #pragma unroll
    for (int j = 0; j < 4; ++j) acc[i][j] = (floatx4){0.f, 0.f, 0.f, 0.f};

  {
    short8 a0 = *(const short8*)(Xb + (size_t)(m0 + sr0) * IDIM + sc0);
    short8 a1 = *(const short8*)(Xb + (size_t)(m0 + sr1) * IDIM + sc1);
    short8 b0 = *(const short8*)(Wb + (size_t)(n0 + sr0) * IDIM + sc0);
    short8 b1 = *(const short8*)(Wb + (size_t)(n0 + sr1) * IDIM + sc1);
    *(short8*)(As[0] + sr0 * 32 + sc0) = a0;
    *(short8*)(As[0] + sr1 * 32 + sc1) = a1;
    *(short8*)(Bs[0] + sr0 * 32 + sc0) = b0;
    *(short8*)(Bs[0] + sr1 * 32 + sc1) = b1;
  }

  for (int t = 0; t < 16; ++t) {
    const int cur = t & 1;
    __syncthreads();
    short8 a0, a1, b0, b1;
    if (t < 15) {
      int k0 = (t + 1) * 32;
      a0 = *(const short8*)(Xb + (size_t)(m0 + sr0) * IDIM + k0 + sc0);
      a1 = *(const short8*)(Xb + (size_t)(m0 + sr1) * IDIM + k0 + sc1);
      b0 = *(const short8*)(Wb + (size_t)(n0 + sr0) * IDIM + k0 + sc0);
      b1 = *(const short8*)(Wb + (size_t)(n0 + sr1) * IDIM + k0 + sc1);
    }
    short8 af[4], bf[4];
    #pragma unroll
    for (int i = 0; i < 4; ++i)
      af[i] = *(const short8*)(As[cur] + (wr * 64 + i * 16 + r16) * 32 + q * 8);
    #pragma unroll
    for (int j = 0; j < 4; ++j)
      bf[j] = *(const short8*)(Bs[cur] + (wc * 64 + j * 16 + r16) * 32 + q * 8);
    #pragma unroll
    for (int i = 0; i < 4; ++i)
      #pragma unroll
      for (int j = 0; j < 4; ++j)
        acc[i][j] = __builtin_amdgcn_mfma_f32_16x16x32_bf16(af[i], bf[j], acc[i][j], 0, 0, 0);
    if (t < 15) {
      *(short8*)(As[cur ^ 1] + sr0 * 32 + sc0) = a0;
      *(short8*)(As[cur ^ 1] + sr1 * 32 + sc1) = a1;
      *(short8*)(Bs[cur ^ 1] + sr0 * 32 + sc0) = b0;
      *(short8*)(Bs[cur ^ 1] + sr1 * 32 + sc1) = b1;
    }
  }

  #pragma unroll
  for (int j = 0; j < 4; ++j) {
    int col = n0 + wc * 64 + j * 16 + r16;
    float bias = bA[col];
    #pragma unroll
    for (int i = 0; i < 4; ++i) {
      #pragma unroll
      for (int jj = 0; jj < 4; ++jj) {
        int row = m0 + wr * 64 + i * 16 + q * 4 + jj;
        GXh[(size_t)row * 1536 + col] = f2bf(acc[i][j][jj] + bias);
      }
    }
  }
}

// ---------------- async persistent recurrent kernel ----------------
__global__ __launch_bounds__(512, 1) void recurrent2(
    const unsigned short* __restrict__ GXh,    // (T*256 x 1536) bf16
    const unsigned short* __restrict__ Wmhh,   // (1536 x 512) bf16 N-major
    const unsigned short* __restrict__ W2,     // (2048 x 1024) bf16 N-major
    const float* __restrict__ bB,              // (2048)
    const float* __restrict__ wd2,             // (32 x 512)
    unsigned short* __restrict__ h1L2,         // chunked, A-XCD L2 copy
    unsigned short* __restrict__ h1LLC,        // chunked, LLC copy for B
    unsigned short* __restrict__ h2his,        // chunked, B-XCD L2
    float* __restrict__ sel,                   // (256 x 512) fp32
    const int* __restrict__ length,
    int* __restrict__ counters) {
  extern __shared__ char lds[];
  const int tid = threadIdx.x;
  const int lane = tid & 63;
  const int wv = tid >> 6;                 // 0..7
  const int q = lane >> 4, r16 = lane & 15;
  const int xcd = (int)blockIdx.x & 7;
  const int bs = xcd >> 1;
  const bool isA = (xcd & 1) == 0;
  const int hs = (int)blockIdx.x >> 3;
  const int hcol = hs * 16 + r16;
  int* aFlags = counters + bs * 1024;
  int* bFlags = counters + 4096 + bs * 1024;

  if (isA) {
    unsigned short* WA = (unsigned short*)lds;                        // [48][520]
    unsigned short* HI = (unsigned short*)(lds + 48 * WA_STRIDE * 2); // 64KB hist
    for (int idx = tid; idx < 48 * 64; idx += 512) {
      int rowi = idx >> 6, kc = idx & 63;
      int g = rowi >> 4, c = rowi & 15;
      const unsigned short* src = Wmhh + ((size_t)(g * 512 + hs * 16 + c)) * 512 + kc * 8;
      *(short8*)(WA + rowi * WA_STRIDE + kc * 8) = *(const short8*)src;
    }
    for (int idx = tid; idx < 4096; idx += 512)
      ((uint4*)HI)[idx] = (uint4){0, 0, 0, 0};
    float wdr[KHIST];
    #pragma unroll
    for (int l = 0; l < KHIST; ++l) wdr[l] = wd2[l * HDIM + hcol];
    __syncthreads();

    const int mi = wv & 3;
    const int m0 = bs * 64 + mi * 16;
    const int rg = mi * 4 + q;
    size_t dhoff = 0;
    unsigned short dh1w[4] = {0, 0, 0, 0};   // deferred h1LLC payload

    for (int s = 0; s < T_STEPS; ++s) {
      // deferred LLC store from the previous step -> issued into poll slack,
      // drained by this step's end drain; B gates its read at aFlags >= t+2.
      if (wv < 4 && s > 0)
        llc_store_4rows32(h1LLC + dhoff, dh1w[0], dh1w[1], dh1w[2], dh1w[3]);
      // GX prefetch (bf16 cached loads; complete during the poll)
      unsigned short gu[12];
      if (wv < 4) {
        #pragma unroll
        for (int j = 0; j < 4; ++j) {
          int row = m0 + q * 4 + j;
          size_t gidx = ((size_t)s * BATCH + row) * 1536 + hcol;
          gu[j]     = GXh[gidx];
          gu[4 + j] = GXh[gidx + 512];
          gu[8 + j] = GXh[gidx + 1024];
        }
      }
      // per-wave self-gated polls
      if (wv < 4) {
        if (s > 0 && lane < 32) {
          const int* f = aFlags + lane * FSTR;
          while (flag_ld_llc(f) < s) __builtin_amdgcn_s_sleep(POLL_SLEEP);
        }
      } else if (wv == 4) {
        int tgt = s - (RDEPTH - 1);        // gates h1LLC[s] ring overwrite
        if (tgt > 0 && lane < 32) {
          const int* f = bFlags + lane * FSTR;
          while (flag_ld_llc(f) < tgt) __builtin_amdgcn_s_sleep(POLL_SLEEP);
        }
      }
      if (wv < 4) {
        short8 af[16];
        if (s > 0) {
          const unsigned short* ab = h1L2 +
              (((size_t)((s - 1) & 15) * 4 + bs) << 15) +
              (size_t)(mi * 16 + r16) * 16 + (q & 1) * 8 + (q >> 1) * 1024;
          #pragma unroll
          for (int kk = 0; kk < 16; ++kk)
            l2_issue_16B(ab + (size_t)kk * 2048, &af[kk]);
        }
        // frac-diff filter (wave-private LDS rows) overlaps the load flight
        float f0 = 0.f, f1 = 0.f, f2 = 0.f, f3 = 0.f;
        #pragma unroll
        for (int jj = 1; jj <= KHIST; ++jj) {
          int sl = (s - jj) & (KHIST - 1);
          ushort4 hv = *(const ushort4*)(HI + ((size_t)(sl * 16 + rg) * 16 + r16) * 4);
          float wc = wdr[jj - 1];
          f0 += wc * bf2f(hv.x); f1 += wc * bf2f(hv.y);
          f2 += wc * bf2f(hv.z); f3 += wc * bf2f(hv.w);
        }
        float fj[4] = {f0, f1, f2, f3};
        floatx4 acc[3];
        #pragma unroll
        for (int g = 0; g < 3; ++g) acc[g] = (floatx4){0.f, 0.f, 0.f, 0.f};
        if (s > 0) {
          drain_vm();                               // af now valid
          __builtin_amdgcn_sched_barrier(0);        // rule #18: keep MFMA below
          #pragma unroll
          for (int kk = 0; kk < 16; ++kk) {
            #pragma unroll
            for (int g = 0; g < 3; ++g) {
              short8 b = *(const short8*)(WA + (size_t)(g * 16 + r16) * WA_STRIDE + kk * 32 + q * 8);
              acc[g] = __builtin_amdgcn_mfma_f32_16x16x32_bf16(af[kk], b, acc[g], 0, 0, 0);
            }
          }
        }
        float c1[4];
        unsigned short h1w[4];
        #pragma unroll
        for (int j = 0; j < 4; ++j) {
          float gI = bf2f(gu[j])     + acc[0][j];
          float gO = bf2f(gu[4 + j]) + acc[1][j];
          float gG = bf2f(gu[8 + j]) + acc[2][j];
          float ig = sigm(gI), og = sigm(gO), cd = tanh_f(gG);
          float c1v = ig * cd - fj[j];
          c1[j] = c1v;
          h1w[j] = f2bf(og * tanh_f(c1v));
        }
        // immediate L2 store for A peers (lockstep +-1 -> ring safe, no gate)
        size_t hoff = (((size_t)(s & 15) * 4 + bs) << 15) + (size_t)hs * 1024 +
                      (size_t)(mi * 16 + q * 4) * 16 + r16;
        l2_store_4rows32(h1L2 + hoff, h1w[0], h1w[1], h1w[2], h1w[3]);
        dhoff = hoff;
        #pragma unroll
        for (int j = 0; j < 4; ++j) dh1w[j] = h1w[j];
        ushort4 hw;
        hw.x = f2bf(c1[0]); hw.y = f2bf(c1[1]); hw.z = f2bf(c1[2]); hw.w = f2bf(c1[3]);
        *(ushort4*)(HI + ((size_t)((s & (KHIST - 1)) * 16 + rg) * 16 + r16) * 4) = hw;
      }
      drain_vm();
      __syncthreads();                     // joins wv4 gate before next deferred store
      if (tid == 0)
        flag_st_llc(aFlags + hs * FSTR, s + 1);
    }
    // tail: flush deferred h1LLC[127] and publish the final gate value
    if (wv < 4)
      llc_store_4rows32(h1LLC + dhoff, dh1w[0], dh1w[1], dh1w[2], dh1w[3]);
    drain_vm();
    __syncthreads();
    if (tid == 0)
      flag_st_llc(aFlags + hs * FSTR, T_STEPS + 1);
  } else {
    // ---- B block (role-swapped) ----
    unsigned short* WB = (unsigned short*)lds;                 // [64][1032]
    float* EX = (float*)(lds + 64 * WB_STRIDE * 2);            // exch [4 mi][4 g][64 lane][4]
    for (int idx = tid; idx < 64 * 128; idx += 512) {
      int rowi = idx >> 7, kc = idx & 127;
      int g = rowi >> 4, c = rowi & 15;
      const unsigned short* src = W2 + ((size_t)(g * 512 + hs * 16 + c)) * 1024 + kc * 8;
      *(short8*)(WB + rowi * WB_STRIDE + kc * 8) = *(const short8*)src;
    }
    const int mi = wv >> 1, kh = wv & 1;
    const int m0 = bs * 64 + mi * 16;
    float c2r[4] = {0.f, 0.f, 0.f, 0.f};
    int lenr[4];
    float bBr[4];
    #pragma unroll
    for (int j = 0; j < 4; ++j) lenr[j] = length[m0 + q * 4 + j];
    #pragma unroll
    for (int g = 0; g < 4; ++g) bBr[g] = bB[g * 512 + hcol];
    __syncthreads();

    for (int t = 0; t < T_STEPS; ++t) {
      // kh=1 (off critical path): h1[t] from A, gated at aFlags >= t+2
      // (covers A's deferred h1LLC[t] stores, drained by A's step t+1).
      // kh=0 (critical): h2[t-1] from B peers, gated at bFlags >= t.
      if (kh == 1) {
        if (lane < 32) {
          const int* f = aFlags + lane * FSTR;
          while (flag_ld_llc(f) < t + 2) __builtin_amdgcn_s_sleep(POLL_SLEEP);
        }
      } else {
        if (t > 0 && lane < 32) {
          const int* f = bFlags + lane * FSTR;
          while (flag_ld_llc(f) < t) __builtin_amdgcn_s_sleep(POLL_SLEEP);
        }
      }
      floatx4 acc[4];
      #pragma unroll
      for (int g = 0; g < 4; ++g) acc[g] = (floatx4){0.f, 0.f, 0.f, 0.f};
      const size_t lrow = (size_t)(mi * 16 + r16) * 16 + (q & 1) * 8 + (q >> 1) * 1024;
      if (kh == 1) {
        // h1-part (k-half 0): compute early, deposit EX before the barrier
        short8 af[16];
        const unsigned short* ab = h1LLC + (((size_t)(t & 15) * 4 + bs) << 15) + lrow;
        #pragma unroll
        for (int kk = 0; kk < 16; ++kk)
          llc_issue_16B(ab + (size_t)kk * 2048, &af[kk]);
        drain_vm();
        __builtin_amdgcn_sched_barrier(0);          // rule #18
        #pragma unroll
        for (int kk = 0; kk < 16; ++kk) {
          #pragma unroll
          for (int g = 0; g < 4; ++g) {
            short8 b = *(const short8*)(WB + (size_t)(g * 16 + r16) * WB_STRIDE + kk * 32 + q * 8);
            acc[g] = __builtin_amdgcn_mfma_f32_16x16x32_bf16(af[kk], b, acc[g], 0, 0, 0);
          }
        }
        #pragma unroll
        for (int g = 0; g < 4; ++g)
          *(floatx4*)(EX + ((size_t)(mi * 4 + g) * 64 + lane) * 4) = acc[g];
      } else if (t > 0) {
        // h2-part (k-half 1): the critical wave computes it directly
        short8 af[16];
        const unsigned short* ab = h2his + (((size_t)((t - 1) & 15) * 4 + bs) << 15) + lrow;
        #pragma unroll
        for (int kk = 0; kk < 16; ++kk)
          l2_issue_16B(ab + (size_t)kk * 2048, &af[kk]);
        drain_vm();
        __builtin_amdgcn_sched_barrier(0);          // rule #18
        #pragma unroll
        for (int kk = 0; kk < 16; ++kk) {
          #pragma unroll
          for (int g = 0; g < 4; ++g) {
            short8 b = *(const short8*)(WB + (size_t)(g * 16 + r16) * WB_STRIDE + 512 + kk * 32 + q * 8);
            acc[g] = __builtin_amdgcn_mfma_f32_16x16x32_bf16(af[kk], b, acc[g], 0, 0, 0);
          }
        }
      }
      __syncthreads();   // EX (h1-part) visible; kh=1 arrived early
      if (kh == 0) {
        #pragma unroll
        for (int g = 0; g < 4; ++g)
          acc[g] += *(const floatx4*)(EX + ((size_t)(mi * 4 + g) * 64 + lane) * 4);
        unsigned short h2w[4];
        #pragma unroll
        for (int j = 0; j < 4; ++j) {
          int row = m0 + q * 4 + j;
          float gi = acc[0][j] + bBr[0];
          float gf = acc[1][j] + bBr[1];
          float gg = acc[2][j] + bBr[2];
          float go = acc[3][j] + bBr[3];
          float c2n = sigm(gf) * c2r[j] + sigm(gi) * tanh_f(gg);
          c2r[j] = c2n;
          float h2n = tanh_f(sigm(go) * tanh_f(c2n));
          h2w[j] = f2bf(h2n);
          if (lenr[j] == t) sel[(size_t)row * 512 + hcol] = h2n;
        }
        size_t hoff = (((size_t)(t & 15) * 4 + bs) << 15) + (size_t)hs * 1024 +
                      (size_t)(mi * 16 + q * 4) * 16 + r16;
        l2_store_4rows32(h2his + hoff, h2w[0], h2w[1], h2w[2], h2w[3]);
      }
      drain_vm();
      __syncthreads();
      if (tid == 0)
        flag_st_llc(bFlags + hs * FSTR, t + 1);
    }
  }
}

// ---------------- output head ----------------
__global__ void out_head_kernel(const float* __restrict__ sel, const float* __restrict__ Wout,
                                const float* __restrict__ bout, float* __restrict__ out) {
  int b = blockIdx.x, lane = threadIdx.x;   // 256 blocks x 64 threads
  float acc[5] = {0.f, 0.f, 0.f, 0.f, 0.f};
  for (int j = lane; j < HDIM; j += 64) {
    float x = sel[(size_t)b * HDIM + j];
    #pragma unroll
    for (int o = 0; o < 5; ++o) acc[o] += x * Wout[o * HDIM + j];
  }
  #pragma unroll
  for (int o = 0; o < 5; ++o)
    for (int off = 32; off > 0; off >>= 1) acc[o] += __shfl_down(acc[o], off);
  if (lane == 0) {
    float v[5]; float m = -1e30f;
    #pragma unroll
    for (int o = 0; o < 5; ++o) { v[o] = acc[o] + bout[o]; m = fmaxf(m, v[o]); }
    float s = 0.f;
    #pragma unroll
    for (int o = 0; o < 5; ++o) s += __expf(v[o] - m);
    float l = logf(s) + m;
    #pragma unroll
    for (int o = 0; o < 5; ++o) out[b * 5 + o] = v[o] - l;
  }
}

// ---------------- launch ----------------
extern "C" void kernel_launch(void* const* d_in, const int* in_sizes, int n_in,
                              void* d_out, int out_size, void* d_ws, size_t ws_size,
                              hipStream_t stream) {
  const float* x      = (const float*)d_in[0];
  const int*   length = (const int*)d_in[1];
  const float* b_d    = (const float*)d_in[2];
  const float* W_mih  = (const float*)d_in[3];
  const float* W_mhh  = (const float*)d_in[4];
  const float* b_mih  = (const float*)d_in[5];
  const float* b_mhh  = (const float*)d_in[6];
  const float* W_ih   = (const float*)d_in[7];
  const float* W_hh   = (const float*)d_in[8];
  const float* b_ih   = (const float*)d_in[9];
  const float* b_hh   = (const float*)d_in[10];
  const float* W_out  = (const float*)d_in[11];
  const float* b_out  = (const float*)d_in[12];
  float* out = (float*)d_out;

  char* ws = (char*)d_ws;
  size_t off = 0;
  auto take = [&](size_t bytes) -> char* {
    char* p = ws + off;
    off += (bytes + 255) & ~(size_t)255;
    return p;
  };

  unsigned short* Xb     = (unsigned short*)take((size_t)T_STEPS * BATCH * IDIM * 2);
  unsigned short* Wmih_b = (unsigned short*)take(1536 * 512 * 2);
  unsigned short* Wmhh_b = (unsigned short*)take(1536 * 512 * 2);
  unsigned short* W2_b   = (unsigned short*)take(2048 * 1024 * 2);
  float* bA  = (float*)take(1536 * 4);
  float* bB  = (float*)take(2048 * 4);
  float* wd2 = (float*)take(KHIST * HDIM * 4);
  unsigned short* h1L2  = (unsigned short*)take((size_t)RDEPTH * BATCH * 512 * 2);
  unsigned short* h1LLC = (unsigned short*)take((size_t)RDEPTH * BATCH * 512 * 2);
  unsigned short* h2his = (unsigned short*)take((size_t)RDEPTH * BATCH * 512 * 2);
  float* sel = (float*)take((size_t)BATCH * HDIM * 4);
  int* counters = (int*)take(32768);
  unsigned short* GXh = (unsigned short*)take((size_t)T_STEPS * BATCH * 1536 * 2);
  if (off > ws_size) return;  // workspace too small -> loud validation failure

  prep_all<<<PREP_BLOCKS, 256, 0, stream>>>(x, W_mih, W_mhh, W_ih, W_hh,
                                            b_d, b_mih, b_mhh, b_ih, b_hh,
                                            Xb, Wmih_b, Wmhh_b, W2_b, wd2, bA, bB, counters);
  // 128x128 tiles: (32768/128) * (1536/128) = 256 * 12 = 3072 blocks, bn-outer
  gx_gemm_kernel<<<3072, 256, 0, stream>>>(Xb, Wmih_b, bA, GXh);

  hipFuncSetAttribute((const void*)recurrent2, hipFuncAttributeMaxDynamicSharedMemorySize, LDS_BYTES);
  void* kargs[] = { (void*)&GXh, (void*)&Wmhh_b, (void*)&W2_b, (void*)&bB, (void*)&wd2,
                    (void*)&h1L2, (void*)&h1LLC, (void*)&h2his, (void*)&sel, (void*)&length,
                    (void*)&counters };
  hipLaunchCooperativeKernel((void*)recurrent2, dim3(256), dim3(512), kargs, LDS_BYTES, stream);

  out_head_kernel<<<BATCH, 64, 0, stream>>>(sel, W_out, b_out, out);
}